// Round 13
// baseline (1307.442 us; speedup 1.0000x reference)
//
#include <hip/hip_runtime.h>
#include <hip/hip_bf16.h>

#define NNODES 100000
#define NEDGES 1600000
#define INF_   128
#define HF     128
#define OUTF   112
#define NLAYERS 4
#define NNETS  3
#define SPMM_BLOCKS 2048
#define SPMM_WAVES  (SPMM_BLOCKS*4)

typedef __attribute__((ext_vector_type(8))) short bf16x8;
typedef __attribute__((ext_vector_type(8))) unsigned short u16x8;
typedef __attribute__((ext_vector_type(4))) float f32x4;
typedef __attribute__((ext_vector_type(2))) float f32x2;
typedef __attribute__((ext_vector_type(2))) unsigned int u32x2;
typedef unsigned long long u64;
typedef unsigned int u32;

__device__ __forceinline__ float bf2f(short u){
  unsigned x = ((unsigned)(unsigned short)u) << 16;
  return __builtin_bit_cast(float, x);
}
__device__ __forceinline__ unsigned short f2bf(float f){
  unsigned u = __builtin_bit_cast(unsigned, f);
  u += 0x7fffu + ((u >> 16) & 1u);   // RNE
  return (unsigned short)(u >> 16);
}
__device__ __forceinline__ float ub(u32 q, int j){ return (float)((q >> (8*j)) & 0xFF); }

// hidden-feature permutation: canonical col c -> stored position p = (c&15)*8 + (c>>4)

// ---------------- int64-vs-int32 edge_index format probe ----------------
__global__ void detect_fmt(const u64* __restrict__ ei64, int* __restrict__ flag){
  u64 v = ei64[threadIdx.x];
  u64 b = __ballot((v >> 32) != 0ull);
  if (threadIdx.x == 0) flag[0] = (b == 0ull) ? 1 : 0;
}

__device__ __forceinline__ int load_dst(const int* ei, int is64, int e){
  return is64 ? ei[2*(NEDGES + e)] : ei[NEDGES + e];
}
__device__ __forceinline__ int load_src(const int* ei, int is64, int e){
  return is64 ? ei[2*e] : ei[e];
}

// ---------------- CSR build ----------------
// hist also records each edge's arrival rank among its dst's edges
__global__ void hist_kernel(const int* __restrict__ ei, const int* __restrict__ flag,
                            int* counts, int* __restrict__ rank){
  int e = blockIdx.x*256 + threadIdx.x;
  if (e < NEDGES){
    int d = load_dst(ei, flag[0], e);
    if ((unsigned)d < NNODES) rank[e] = atomicAdd(&counts[d], 1);
  }
}

__global__ __launch_bounds__(256) void scan1(const int* __restrict__ counts,
                                             int* __restrict__ scanned,
                                             int* __restrict__ partials){
  __shared__ int s[256];
  int t = threadIdx.x, i = blockIdx.x*256 + t;
  int v = (i < NNODES) ? counts[i] : 0;
  s[t] = v; __syncthreads();
  for (int off=1; off<256; off<<=1){
    int a = (t >= off) ? s[t-off] : 0;
    __syncthreads();
    s[t] += a;
    __syncthreads();
  }
  if (i < NNODES) scanned[i] = s[t] - v;
  if (t == 255) partials[blockIdx.x] = s[255];
}

__global__ __launch_bounds__(512) void scan2(int* partials, int G){
  __shared__ int s[512];
  int t = threadIdx.x;
  int v = (t < G) ? partials[t] : 0;
  s[t] = v; __syncthreads();
  for (int off=1; off<512; off<<=1){
    int a = (t >= off) ? s[t-off] : 0;
    __syncthreads();
    s[t] += a;
    __syncthreads();
  }
  if (t < G) partials[t] = s[t] - v;
}

__global__ void scan3(const int* __restrict__ scanned, const int* __restrict__ partials,
                      int* __restrict__ row_ptr){
  int i = blockIdx.x*256 + threadIdx.x;
  if (i < NNODES){
    row_ptr[i] = scanned[i] + partials[i>>8];
  } else if (i == NNODES){
    row_ptr[NNODES] = NEDGES;
  }
}

// positional scatter: no atomics — pos = row_ptr[dst] + rank[e]
// packed meta: bits[16:0]=src, bits[31:17]=weight as sign-less bf16
__global__ void scatter_kernel(const int* __restrict__ ei, const float* __restrict__ ew,
                               const int* __restrict__ flag,
                               const int* __restrict__ row_ptr, const int* __restrict__ rank,
                               u32* __restrict__ meta){
  int e = blockIdx.x*256 + threadIdx.x;
  if (e < NEDGES){
    int is64 = flag[0];
    int s = load_src(ei, is64, e);
    int d = load_dst(ei, is64, e);
    float w = __builtin_nontemporal_load(&ew[e]);
    if ((unsigned)d < NNODES && (unsigned)s < NNODES){
      int pos = row_ptr[d] + rank[e];
      if ((unsigned)pos < NEDGES){
        u32 wb = __builtin_bit_cast(u32, w);
        u32 w15 = ((wb + 0x8000u) >> 16) & 0x7FFFu;
        __builtin_nontemporal_store((w15 << 17) | (u32)s, &meta[pos]);
      }
    }
  }
}

// ---------------- weight prep (fp32 -> bf16, transposed; cwt/w1t K pre-permuted by pi^-1) ----------------
__global__ void prep_w(const float* __restrict__ w0, const float* __restrict__ cw,
                       const float* __restrict__ w1,
                       short* __restrict__ w0t, short* __restrict__ cwt, short* __restrict__ w1t){
  int i = blockIdx.x*256 + threadIdx.x;
  const int n0 = NNETS*HF*HF;
  const int n1 = NNETS*NLAYERS*HF*HF;
  const int n2 = NNETS*OUTF*HF;
  if (i < n0){
    int net = i/(HF*HF), r = i%(HF*HF), c = r/HF, k = r%HF;
    w0t[i] = (short)f2bf(w0[(size_t)net*HF*HF + k*HF + c]);
  } else if (i < n0 + n1){
    int j = i - n0;
    int nl = j/(HF*HF), r = j%(HF*HF), c = r/HF, kp = r%HF;
    int k = ((kp&7)<<4) | (kp>>3);                 // pi^-1
    cwt[j] = (short)f2bf(cw[(size_t)nl*HF*HF + k*HF + c]);
  } else if (i < n0 + n1 + n2){
    int j = i - n0 - n1;
    int net = j/(OUTF*HF), r = j%(OUTF*HF), c = r/HF, kp = r%HF;
    int k = ((kp&7)<<4) | (kp>>3);                 // pi^-1
    w1t[j] = (short)f2bf(w1[(size_t)net*HF*OUTF + k*OUTF + c]);
  }
}

// ---------------- input GEMM: h0 = relu(x @ w0 + b0) -> h8/sc AND x08/scx (identical) ----------------
__global__ __launch_bounds__(256) void gemm_in(
    const float* __restrict__ x, const short* __restrict__ w0t, const float* __restrict__ b0,
    unsigned char* __restrict__ h8, float* __restrict__ sc,
    unsigned char* __restrict__ x08, float* __restrict__ scx)
{
  __shared__ short As[128*128];
  const int t = threadIdx.x;
  const int rowBase = blockIdx.x * 128;
  #pragma unroll
  for (int it=0; it<8; ++it){
    int r = it*16 + (t>>4);
    int k = (t&15)*8;
    int gr = rowBase + r;
    bf16x8 v = {0,0,0,0,0,0,0,0};
    if (gr < NNODES){
      f32x4 f0 = __builtin_nontemporal_load((const f32x4*)&x[(size_t)gr*128 + k]);
      f32x4 f1 = __builtin_nontemporal_load((const f32x4*)&x[(size_t)gr*128 + k + 4]);
      v[0]=(short)f2bf(f0[0]); v[1]=(short)f2bf(f0[1]); v[2]=(short)f2bf(f0[2]); v[3]=(short)f2bf(f0[3]);
      v[4]=(short)f2bf(f1[0]); v[5]=(short)f2bf(f1[1]); v[6]=(short)f2bf(f1[2]); v[7]=(short)f2bf(f1[3]);
    }
    *(bf16x8*)&As[r*128 + (k ^ ((r&7)<<3))] = v;
  }
  __syncthreads();

  const int wid = t>>6, lane = t&63;
  const int l16 = lane&15, kg = lane>>4;
  for (int net=0; net<NNETS; ++net){
    const short* Wt = w0t + (size_t)net*HF*HF;
    f32x4 acc[2][8];
    #pragma unroll
    for (int mt=0; mt<2; ++mt)
      #pragma unroll
      for (int nt=0; nt<8; ++nt){ acc[mt][nt][0]=0.f; acc[mt][nt][1]=0.f; acc[mt][nt][2]=0.f; acc[mt][nt][3]=0.f; }
    #pragma unroll
    for (int ks=0; ks<4; ++ks){
      int k0 = ks*32 + kg*8;
      bf16x8 a0, a1;
      { int r = wid*32 + l16;      a0 = *(const bf16x8*)&As[r*128 + (k0 ^ ((r&7)<<3))]; }
      { int r = wid*32 + 16 + l16; a1 = *(const bf16x8*)&As[r*128 + (k0 ^ ((r&7)<<3))]; }
      #pragma unroll
      for (int nt=0; nt<8; ++nt){
        bf16x8 b = *(const bf16x8*)&Wt[(size_t)(nt*16 + l16)*128 + k0];
        acc[0][nt] = __builtin_amdgcn_mfma_f32_16x16x32_bf16(a0, b, acc[0][nt], 0, 0, 0);
        acc[1][nt] = __builtin_amdgcn_mfma_f32_16x16x32_bf16(a1, b, acc[1][nt], 0, 0, 0);
      }
    }
    #pragma unroll
    for (int mt=0; mt<2; ++mt){
      #pragma unroll
      for (int j=0; j<4; ++j){
        int row = rowBase + wid*32 + mt*16 + kg*4 + j;
        float v[8]; float mx = 0.f;
        #pragma unroll
        for (int nt=0; nt<8; ++nt){
          float f = fmaxf(acc[mt][nt][j] + b0[net*HF + nt*16 + l16], 0.f);
          v[nt] = f; mx = fmaxf(mx, f);
        }
        #pragma unroll
        for (int off=1; off<16; off<<=1) mx = fmaxf(mx, __shfl_xor(mx, off));
        if (row < NNODES){
          float inv = (mx > 0.f) ? 255.f/mx : 0.f;
          u32 d0=0, d1=0;
          #pragma unroll
          for (int nt=0; nt<4; ++nt) d0 |= ((u32)(v[nt]*inv + 0.5f)) << (8*nt);
          #pragma unroll
          for (int nt=0; nt<4; ++nt) d1 |= ((u32)(v[4+nt]*inv + 0.5f)) << (8*nt);
          u32x2 pk; pk[0]=d0; pk[1]=d1;
          size_t off8 = (size_t)row*384 + net*128 + l16*8;
          *(u32x2*)&h8 [off8] = pk;
          *(u32x2*)&x08[off8] = pk;
          if (l16 == 0){ float s = mx * (1.f/255.f); sc[row*4 + net] = s; scx[row*4 + net] = s; }
        }
      }
    }
  }
}

// ---------------- mid GEMM: t = 0.9*agg8 + 0.1*x08 (dequant-combine in staging);
//                  h = relu((1-beta)*t + beta*(t @ cw)) -> h8/sc ----------------
__global__ __launch_bounds__(256) void gemm_mid(
    const unsigned char* __restrict__ agg8, const float* __restrict__ sca,
    const unsigned char* __restrict__ x08,  const float* __restrict__ scx,
    const short* __restrict__ W, const float beta,
    unsigned char* __restrict__ h8, float* __restrict__ sc)
{
  __shared__ short As[128*128];
  const int t = threadIdx.x;
  const int net = blockIdx.y;
  const int rowBase = blockIdx.x * 128;
  const short* Wt = W + (size_t)net*NLAYERS*HF*HF;

  #pragma unroll
  for (int it=0; it<8; ++it){
    int r = it*16 + (t>>4);
    int k = (t&15)*8;
    int gr = rowBase + r;
    bf16x8 v = {0,0,0,0,0,0,0,0};
    if (gr < NNODES){
      size_t off8 = (size_t)gr*384 + net*128 + k;
      u32x2 da = *(const u32x2*)&agg8[off8];
      u32x2 dx = *(const u32x2*)&x08[off8];
      float sa = 0.9f * sca[gr*4 + net];
      float sx = 0.1f * scx[gr*4 + net];
      #pragma unroll
      for (int j=0; j<4; ++j) v[j]   = (short)f2bf(sa*ub(da[0],j) + sx*ub(dx[0],j));
      #pragma unroll
      for (int j=0; j<4; ++j) v[4+j] = (short)f2bf(sa*ub(da[1],j) + sx*ub(dx[1],j));
    }
    *(bf16x8*)&As[r*128 + (k ^ ((r&7)<<3))] = v;
  }
  __syncthreads();

  const int wid = t>>6, lane = t&63;
  const int l16 = lane&15, kg = lane>>4;
  f32x4 acc[2][8];
  #pragma unroll
  for (int mt=0; mt<2; ++mt)
    #pragma unroll
    for (int nt=0; nt<8; ++nt){ acc[mt][nt][0]=0.f; acc[mt][nt][1]=0.f; acc[mt][nt][2]=0.f; acc[mt][nt][3]=0.f; }

  #pragma unroll
  for (int ks=0; ks<4; ++ks){
    int k0 = ks*32 + kg*8;
    bf16x8 a0, a1;
    { int r = wid*32 + l16;      a0 = *(const bf16x8*)&As[r*128 + (k0 ^ ((r&7)<<3))]; }
    { int r = wid*32 + 16 + l16; a1 = *(const bf16x8*)&As[r*128 + (k0 ^ ((r&7)<<3))]; }
    #pragma unroll
    for (int nt=0; nt<8; ++nt){
      bf16x8 b = *(const bf16x8*)&Wt[(size_t)(nt*16 + l16)*128 + k0];
      acc[0][nt] = __builtin_amdgcn_mfma_f32_16x16x32_bf16(a0, b, acc[0][nt], 0, 0, 0);
      acc[1][nt] = __builtin_amdgcn_mfma_f32_16x16x32_bf16(a1, b, acc[1][nt], 0, 0, 0);
    }
  }

  #pragma unroll
  for (int mt=0; mt<2; ++mt){
    #pragma unroll
    for (int j=0; j<4; ++j){
      int rl  = wid*32 + mt*16 + kg*4 + j;
      int row = rowBase + rl;
      float v[8]; float mx = 0.f;
      #pragma unroll
      for (int nt=0; nt<8; ++nt){
        int p = l16*8 + nt;                        // pi(col)
        float av = bf2f(As[rl*128 + (p ^ ((rl&7)<<3))]);
        float f = fmaxf((1.f-beta)*av + beta*acc[mt][nt][j], 0.f);
        v[nt] = f; mx = fmaxf(mx, f);
      }
      #pragma unroll
      for (int off=1; off<16; off<<=1) mx = fmaxf(mx, __shfl_xor(mx, off));
      if (row < NNODES){
        float inv = (mx > 0.f) ? 255.f/mx : 0.f;
        u32 d0=0, d1=0;
        #pragma unroll
        for (int nt=0; nt<4; ++nt) d0 |= ((u32)(v[nt]*inv + 0.5f)) << (8*nt);
        #pragma unroll
        for (int nt=0; nt<4; ++nt) d1 |= ((u32)(v[4+nt]*inv + 0.5f)) << (8*nt);
        u32x2 pk; pk[0]=d0; pk[1]=d1;
        *(u32x2*)&h8[(size_t)row*384 + net*128 + l16*8] = pk;
        if (l16 == 0) sc[row*4 + net] = mx * (1.f/255.f);
      }
    }
  }
}

// ---------------- output GEMM: dequant-stage h8, logits+log_softmax+ensemble mean ----------------
__global__ __launch_bounds__(256) void gemm_out(
    const unsigned char* __restrict__ h8, const float* __restrict__ sc,
    const short* __restrict__ w1t, const float* __restrict__ b1,
    float* __restrict__ out)
{
  __shared__ short As[128*128];
  const int t = threadIdx.x;
  const int rowBase = blockIdx.x * 128;
  const int wid = t>>6, lane = t&63;
  const int l16 = lane&15, kg = lane>>4;

  f32x4 sum[2][7];
  #pragma unroll
  for (int mt=0; mt<2; ++mt)
    #pragma unroll
    for (int nt=0; nt<7; ++nt){ sum[mt][nt][0]=0.f; sum[mt][nt][1]=0.f; sum[mt][nt][2]=0.f; sum[mt][nt][3]=0.f; }

  for (int net=0; net<NNETS; ++net){
    __syncthreads();
    #pragma unroll
    for (int it=0; it<8; ++it){
      int r = it*16 + (t>>4);
      int k = (t&15)*8;
      int gr = rowBase + r;
      bf16x8 v = {0,0,0,0,0,0,0,0};
      if (gr < NNODES){
        u32x2 d = *(const u32x2*)&h8[(size_t)gr*384 + net*128 + k];
        float s = sc[gr*4 + net];
        #pragma unroll
        for (int j=0; j<4; ++j) v[j]   = (short)f2bf(s * ub(d[0],j));
        #pragma unroll
        for (int j=0; j<4; ++j) v[4+j] = (short)f2bf(s * ub(d[1],j));
      }
      *(bf16x8*)&As[r*128 + (k ^ ((r&7)<<3))] = v;
    }
    __syncthreads();

    const short* Wt = w1t + (size_t)net*OUTF*HF;
    f32x4 acc[2][7];
    #pragma unroll
    for (int mt=0; mt<2; ++mt)
      #pragma unroll
      for (int nt=0; nt<7; ++nt){ acc[mt][nt][0]=0.f; acc[mt][nt][1]=0.f; acc[mt][nt][2]=0.f; acc[mt][nt][3]=0.f; }
    #pragma unroll
    for (int ks=0; ks<4; ++ks){
      int k0 = ks*32 + kg*8;
      bf16x8 a0, a1;
      { int r = wid*32 + l16;      a0 = *(const bf16x8*)&As[r*128 + (k0 ^ ((r&7)<<3))]; }
      { int r = wid*32 + 16 + l16; a1 = *(const bf16x8*)&As[r*128 + (k0 ^ ((r&7)<<3))]; }
      #pragma unroll
      for (int nt=0; nt<7; ++nt){
        bf16x8 b = *(const bf16x8*)&Wt[(size_t)(nt*16 + l16)*128 + k0];
        acc[0][nt] = __builtin_amdgcn_mfma_f32_16x16x32_bf16(a0, b, acc[0][nt], 0, 0, 0);
        acc[1][nt] = __builtin_amdgcn_mfma_f32_16x16x32_bf16(a1, b, acc[1][nt], 0, 0, 0);
      }
    }
    #pragma unroll
    for (int mt=0; mt<2; ++mt)
      #pragma unroll
      for (int nt=0; nt<7; ++nt){
        float b = b1[net*OUTF + nt*16 + l16];
        #pragma unroll
        for (int j=0; j<4; ++j) acc[mt][nt][j] += b;
      }
    #pragma unroll
    for (int mt=0; mt<2; ++mt){
      #pragma unroll
      for (int j=0; j<4; ++j){
        float m = -3.4e38f;
        #pragma unroll
        for (int nt=0; nt<7; ++nt) m = fmaxf(m, acc[mt][nt][j]);
        #pragma unroll
        for (int k=1; k<16; k<<=1) m = fmaxf(m, __shfl_xor(m, k));
        float e = 0.f;
        #pragma unroll
        for (int nt=0; nt<7; ++nt) e += expf(acc[mt][nt][j] - m);
        #pragma unroll
        for (int k=1; k<16; k<<=1) e += __shfl_xor(e, k);
        float lse = m + logf(e);
        #pragma unroll
        for (int nt=0; nt<7; ++nt) sum[mt][nt][j] += acc[mt][nt][j] - lse;
      }
    }
  }

  #pragma unroll
  for (int mt=0; mt<2; ++mt){
    #pragma unroll
    for (int nt=0; nt<7; ++nt){
      #pragma unroll
      for (int j=0; j<4; ++j){
        int row = rowBase + wid*32 + mt*16 + kg*4 + j;
        if (row < NNODES)
          __builtin_nontemporal_store(sum[mt][nt][j] * (1.f/3.f),
                                      &out[(size_t)row*OUTF + nt*16 + l16]);
      }
    }
  }
}

// ---------------- SpMM (pure gather, work-balanced persistent waves): agg8 = quant(A @ h8) ----------------
// each wave grid-strides over ~12 nodes -> all waves finish together; quarter-wave per edge
__global__ __launch_bounds__(256) void spmm3(
    const int* __restrict__ row_ptr, const u32* __restrict__ meta,
    const unsigned char* __restrict__ h8, const float* __restrict__ sc,
    unsigned char* __restrict__ agg8, float* __restrict__ sca)
{
  const int wgid = blockIdx.x*4 + (threadIdx.x>>6);
  const int lane = threadIdx.x & 63;
  const int q    = lane >> 4;
  const int l16  = lane & 15;
  const u32 base_l = (u32)l16*8;

  for (int node = wgid; node < NNODES; node += SPMM_WAVES){
    int start = row_ptr[node], end = row_ptr[node+1];
    float acc[3][8] = {{0.f},{0.f},{0.f}};
    int e = start + q;
    for (; e + 4 < end; e += 8){
      u32 m0 = __builtin_nontemporal_load(&meta[e]);
      u32 m1 = __builtin_nontemporal_load(&meta[e+4]);
      u32 s0 = m0 & 0x1FFFFu, s1 = m1 & 0x1FFFFu;
      u32 o0 = (s0<<8) + (s0<<7) + base_l;     // s0*384 + l16*8
      u32 o1 = (s1<<8) + (s1<<7) + base_l;
      float w0 = __builtin_bit_cast(float, (m0 >> 17) << 16);
      float w1 = __builtin_bit_cast(float, (m1 >> 17) << 16);
      f32x4 c0 = *(const f32x4*)&sc[s0*4];
      f32x4 c1 = *(const f32x4*)&sc[s1*4];
      u32x2 a0 = *(const u32x2*)(h8 + o0);
      u32x2 a1 = *(const u32x2*)(h8 + o0 + 128);
      u32x2 a2 = *(const u32x2*)(h8 + o0 + 256);
      u32x2 b0 = *(const u32x2*)(h8 + o1);
      u32x2 b1 = *(const u32x2*)(h8 + o1 + 128);
      u32x2 b2 = *(const u32x2*)(h8 + o1 + 256);
      float ws00 = w0*c0[0], ws01 = w0*c0[1], ws02 = w0*c0[2];
      float ws10 = w1*c1[0], ws11 = w1*c1[1], ws12 = w1*c1[2];
      #pragma unroll
      for (int j=0;j<4;++j){
        acc[0][j]   += ws00*ub(a0[0],j) + ws10*ub(b0[0],j);
        acc[0][j+4] += ws00*ub(a0[1],j) + ws10*ub(b0[1],j);
        acc[1][j]   += ws01*ub(a1[0],j) + ws11*ub(b1[0],j);
        acc[1][j+4] += ws01*ub(a1[1],j) + ws11*ub(b1[1],j);
        acc[2][j]   += ws02*ub(a2[0],j) + ws12*ub(b2[0],j);
        acc[2][j+4] += ws02*ub(a2[1],j) + ws12*ub(b2[1],j);
      }
    }
    for (; e < end; e += 4){
      u32 m0 = __builtin_nontemporal_load(&meta[e]);
      u32 s0 = m0 & 0x1FFFFu;
      u32 o0 = (s0<<8) + (s0<<7) + base_l;
      float w0 = __builtin_bit_cast(float, (m0 >> 17) << 16);
      f32x4 c0 = *(const f32x4*)&sc[s0*4];
      u32x2 a0 = *(const u32x2*)(h8 + o0);
      u32x2 a1 = *(const u32x2*)(h8 + o0 + 128);
      u32x2 a2 = *(const u32x2*)(h8 + o0 + 256);
      float ws00 = w0*c0[0], ws01 = w0*c0[1], ws02 = w0*c0[2];
      #pragma unroll
      for (int j=0;j<4;++j){
        acc[0][j]   += ws00*ub(a0[0],j);
        acc[0][j+4] += ws00*ub(a0[1],j);
        acc[1][j]   += ws01*ub(a1[0],j);
        acc[1][j+4] += ws01*ub(a1[1],j);
        acc[2][j]   += ws02*ub(a2[0],j);
        acc[2][j+4] += ws02*ub(a2[1],j);
      }
    }
    #pragma unroll
    for (int n=0;n<3;++n)
      #pragma unroll
      for (int j=0;j<8;++j){
        acc[n][j] += __shfl_xor(acc[n][j], 16);
        acc[n][j] += __shfl_xor(acc[n][j], 32);
      }
    // per-(node,net) int8 quant of agg: q-th 16-lane group handles net q
    if (q < 3){
      float mx = 0.f;
      #pragma unroll
      for (int j=0;j<8;++j) mx = fmaxf(mx, acc[q][j]);
      #pragma unroll
      for (int off=1; off<16; off<<=1) mx = fmaxf(mx, __shfl_xor(mx, off));
      float inv = (mx > 0.f) ? 255.f/mx : 0.f;
      u32 d0=0, d1=0;
      #pragma unroll
      for (int j=0;j<4;++j) d0 |= ((u32)(acc[q][j]*inv + 0.5f)) << (8*j);
      #pragma unroll
      for (int j=0;j<4;++j) d1 |= ((u32)(acc[q][4+j]*inv + 0.5f)) << (8*j);
      u32x2 pk; pk[0]=d0; pk[1]=d1;
      *(u32x2*)&agg8[(size_t)node*384 + q*128 + base_l] = pk;
      if (l16 == 0) sca[node*4 + q] = mx * (1.f/255.f);
    }
  }
}

extern "C" void kernel_launch(void* const* d_in, const int* in_sizes, int n_in,
                              void* d_out, int out_size, void* d_ws, size_t ws_size,
                              hipStream_t stream){
  const float* x  = (const float*)d_in[0];
  const int*   ei = (const int*)d_in[1];
  const float* ew = (const float*)d_in[2];
  const float* w0 = (const float*)d_in[3];
  const float* b0 = (const float*)d_in[4];
  const float* w1 = (const float*)d_in[5];
  const float* b1 = (const float*)d_in[6];
  const float* cw = (const float*)d_in[7];
  float* out = (float*)d_out;

  char* ws = (char*)d_ws;
  size_t o = 0;
  auto alloc = [&](size_t b){ size_t r = o; o += (b + 255) & ~(size_t)255; return r; };
  int*   flag     = (int*)(ws + alloc(256));
  int*   counts   = (int*)(ws + alloc((size_t)NNODES*4));
  int*   scanned  = (int*)(ws + alloc((size_t)NNODES*4));
  int*   row_ptr  = (int*)(ws + alloc((size_t)(NNODES+1)*4));
  int*   partials = (int*)(ws + alloc(512*4));
  int*   rank     = (int*)(ws + alloc((size_t)NEDGES*4));
  u32*   meta     = (u32*)(ws + alloc((size_t)NEDGES*4));
  short* w0t = (short*)(ws + alloc((size_t)NNETS*HF*HF*2));
  short* cwt = (short*)(ws + alloc((size_t)NNETS*NLAYERS*HF*HF*2));
  short* w1t = (short*)(ws + alloc((size_t)NNETS*OUTF*HF*2));
  unsigned char* h8   = (unsigned char*)(ws + alloc((size_t)NNODES*NNETS*128));
  float* sc  = (float*)(ws + alloc((size_t)NNODES*4*4));
  unsigned char* x08  = (unsigned char*)(ws + alloc((size_t)NNODES*NNETS*128));
  float* scx = (float*)(ws + alloc((size_t)NNODES*4*4));
  unsigned char* agg8 = (unsigned char*)(ws + alloc((size_t)NNODES*NNETS*128));
  float* sca = (float*)(ws + alloc((size_t)NNODES*4*4));
  (void)ws_size; (void)in_sizes; (void)n_in; (void)out_size;
  // total ws use ~137 MB

  hipMemsetAsync(counts, 0, (size_t)NNODES*4, stream);
  detect_fmt    <<<1,   64,  0, stream>>>((const u64*)ei, flag);
  hist_kernel   <<<6250,256, 0, stream>>>(ei, flag, counts, rank);
  scan1         <<<391, 256, 0, stream>>>(counts, scanned, partials);
  scan2         <<<1,   512, 0, stream>>>(partials, 391);
  scan3         <<<391, 256, 0, stream>>>(scanned, partials, row_ptr);
  scatter_kernel<<<6250,256, 0, stream>>>(ei, ew, flag, row_ptr, rank, meta);

  prep_w<<<1128, 256, 0, stream>>>(w0, cw, w1, w0t, cwt, w1t);

  gemm_in<<<782, 256, 0, stream>>>(x, w0t, b0, h8, sc, x08, scx);
  for (int l=0; l<NLAYERS; ++l){
    float beta = logf(0.5f/(float)(l+1) + 1.0f);
    spmm3<<<SPMM_BLOCKS, 256, 0, stream>>>(row_ptr, meta, h8, sc, agg8, sca);
    gemm_mid<<<dim3(782,3), 256, 0, stream>>>(agg8, sca, x08, scx,
                                              cwt + (size_t)l*HF*HF, beta, h8, sc);
  }
  gemm_out<<<782, 256, 0, stream>>>(h8, sc, w1t, b1, out);
}

// Round 14
// 1194.177 us; speedup vs baseline: 1.0948x; 1.0948x over previous
//
#include <hip/hip_runtime.h>
#include <hip/hip_bf16.h>

#define NNODES 100000
#define NEDGES 1600000
#define INF_   128
#define HF     128
#define OUTF   112
#define NLAYERS 4
#define NNETS  3

typedef __attribute__((ext_vector_type(8))) short bf16x8;
typedef __attribute__((ext_vector_type(8))) unsigned short u16x8;
typedef __attribute__((ext_vector_type(4))) float f32x4;
typedef __attribute__((ext_vector_type(2))) float f32x2;
typedef __attribute__((ext_vector_type(2))) unsigned int u32x2;
typedef unsigned long long u64;
typedef unsigned int u32;

__device__ __forceinline__ float bf2f(short u){
  unsigned x = ((unsigned)(unsigned short)u) << 16;
  return __builtin_bit_cast(float, x);
}
__device__ __forceinline__ unsigned short f2bf(float f){
  unsigned u = __builtin_bit_cast(unsigned, f);
  u += 0x7fffu + ((u >> 16) & 1u);   // RNE
  return (unsigned short)(u >> 16);
}
__device__ __forceinline__ float ub(u32 q, int j){ return (float)((q >> (8*j)) & 0xFF); }
__device__ __forceinline__ f32x2 ub2(u32 q, int hi){
  f32x2 r;
  r[0] = (float)((q >> (hi ? 16 : 0)) & 0xFF);
  r[1] = (float)((q >> (hi ? 24 : 8)) & 0xFF);
  return r;
}

// hidden-feature permutation: canonical col c -> stored position p = (c&15)*8 + (c>>4)

// ---------------- int64-vs-int32 edge_index format probe ----------------
__global__ void detect_fmt(const u64* __restrict__ ei64, int* __restrict__ flag){
  u64 v = ei64[threadIdx.x];
  u64 b = __ballot((v >> 32) != 0ull);
  if (threadIdx.x == 0) flag[0] = (b == 0ull) ? 1 : 0;
}

__device__ __forceinline__ int load_dst(const int* ei, int is64, int e){
  return is64 ? ei[2*(NEDGES + e)] : ei[NEDGES + e];
}
__device__ __forceinline__ int load_src(const int* ei, int is64, int e){
  return is64 ? ei[2*e] : ei[e];
}

// ---------------- CSR build (de-atomic scatter) ----------------
__global__ void hist_kernel(const int* __restrict__ ei, const int* __restrict__ flag,
                            int* counts, int* __restrict__ rank){
  int e = blockIdx.x*256 + threadIdx.x;
  if (e < NEDGES){
    int d = load_dst(ei, flag[0], e);
    if ((unsigned)d < NNODES) rank[e] = atomicAdd(&counts[d], 1);
  }
}

__global__ __launch_bounds__(256) void scan1(const int* __restrict__ counts,
                                             int* __restrict__ scanned,
                                             int* __restrict__ partials){
  __shared__ int s[256];
  int t = threadIdx.x, i = blockIdx.x*256 + t;
  int v = (i < NNODES) ? counts[i] : 0;
  s[t] = v; __syncthreads();
  for (int off=1; off<256; off<<=1){
    int a = (t >= off) ? s[t-off] : 0;
    __syncthreads();
    s[t] += a;
    __syncthreads();
  }
  if (i < NNODES) scanned[i] = s[t] - v;
  if (t == 255) partials[blockIdx.x] = s[255];
}

__global__ __launch_bounds__(512) void scan2(int* partials, int G){
  __shared__ int s[512];
  int t = threadIdx.x;
  int v = (t < G) ? partials[t] : 0;
  s[t] = v; __syncthreads();
  for (int off=1; off<512; off<<=1){
    int a = (t >= off) ? s[t-off] : 0;
    __syncthreads();
    s[t] += a;
    __syncthreads();
  }
  if (t < G) partials[t] = s[t] - v;
}

__global__ void scan3(const int* __restrict__ scanned, const int* __restrict__ partials,
                      int* __restrict__ row_ptr){
  int i = blockIdx.x*256 + threadIdx.x;
  if (i < NNODES){
    row_ptr[i] = scanned[i] + partials[i>>8];
  } else if (i == NNODES){
    row_ptr[NNODES] = NEDGES;
  }
}

// positional scatter: pos = row_ptr[dst] + rank[e]  (no atomics)
// packed meta: bits[16:0]=src, bits[31:17]=weight as sign-less bf16
__global__ void scatter_kernel(const int* __restrict__ ei, const float* __restrict__ ew,
                               const int* __restrict__ flag,
                               const int* __restrict__ row_ptr, const int* __restrict__ rank,
                               u32* __restrict__ meta){
  int e = blockIdx.x*256 + threadIdx.x;
  if (e < NEDGES){
    int is64 = flag[0];
    int s = load_src(ei, is64, e);
    int d = load_dst(ei, is64, e);
    float w = __builtin_nontemporal_load(&ew[e]);
    if ((unsigned)d < NNODES && (unsigned)s < NNODES){
      int pos = row_ptr[d] + rank[e];
      if ((unsigned)pos < NEDGES){
        u32 wb = __builtin_bit_cast(u32, w);
        u32 w15 = ((wb + 0x8000u) >> 16) & 0x7FFFu;
        __builtin_nontemporal_store((w15 << 17) | (u32)s, &meta[pos]);
      }
    }
  }
}

// ---------------- weight prep (fp32 -> bf16, transposed; cwt/w1t K pre-permuted by pi^-1) ----------------
__global__ void prep_w(const float* __restrict__ w0, const float* __restrict__ cw,
                       const float* __restrict__ w1,
                       short* __restrict__ w0t, short* __restrict__ cwt, short* __restrict__ w1t){
  int i = blockIdx.x*256 + threadIdx.x;
  const int n0 = NNETS*HF*HF;
  const int n1 = NNETS*NLAYERS*HF*HF;
  const int n2 = NNETS*OUTF*HF;
  if (i < n0){
    int net = i/(HF*HF), r = i%(HF*HF), c = r/HF, k = r%HF;
    w0t[i] = (short)f2bf(w0[(size_t)net*HF*HF + k*HF + c]);
  } else if (i < n0 + n1){
    int j = i - n0;
    int nl = j/(HF*HF), r = j%(HF*HF), c = r/HF, kp = r%HF;
    int k = ((kp&7)<<4) | (kp>>3);                 // pi^-1
    cwt[j] = (short)f2bf(cw[(size_t)nl*HF*HF + k*HF + c]);
  } else if (i < n0 + n1 + n2){
    int j = i - n0 - n1;
    int net = j/(OUTF*HF), r = j%(OUTF*HF), c = r/HF, kp = r%HF;
    int k = ((kp&7)<<4) | (kp>>3);                 // pi^-1
    w1t[j] = (short)f2bf(w1[(size_t)net*HF*OUTF + k*OUTF + c]);
  }
}

// ---------------- input GEMM: h0 = relu(x @ w0 + b0) -> h8/sc AND x08/scx (identical) ----------------
__global__ __launch_bounds__(256) void gemm_in(
    const float* __restrict__ x, const short* __restrict__ w0t, const float* __restrict__ b0,
    unsigned char* __restrict__ h8, float* __restrict__ sc,
    unsigned char* __restrict__ x08, float* __restrict__ scx)
{
  __shared__ short As[128*128];
  const int t = threadIdx.x;
  const int rowBase = blockIdx.x * 128;
  #pragma unroll
  for (int it=0; it<8; ++it){
    int r = it*16 + (t>>4);
    int k = (t&15)*8;
    int gr = rowBase + r;
    bf16x8 v = {0,0,0,0,0,0,0,0};
    if (gr < NNODES){
      f32x4 f0 = __builtin_nontemporal_load((const f32x4*)&x[(size_t)gr*128 + k]);
      f32x4 f1 = __builtin_nontemporal_load((const f32x4*)&x[(size_t)gr*128 + k + 4]);
      v[0]=(short)f2bf(f0[0]); v[1]=(short)f2bf(f0[1]); v[2]=(short)f2bf(f0[2]); v[3]=(short)f2bf(f0[3]);
      v[4]=(short)f2bf(f1[0]); v[5]=(short)f2bf(f1[1]); v[6]=(short)f2bf(f1[2]); v[7]=(short)f2bf(f1[3]);
    }
    *(bf16x8*)&As[r*128 + (k ^ ((r&7)<<3))] = v;
  }
  __syncthreads();

  const int wid = t>>6, lane = t&63;
  const int l16 = lane&15, kg = lane>>4;
  for (int net=0; net<NNETS; ++net){
    const short* Wt = w0t + (size_t)net*HF*HF;
    f32x4 acc[2][8];
    #pragma unroll
    for (int mt=0; mt<2; ++mt)
      #pragma unroll
      for (int nt=0; nt<8; ++nt){ acc[mt][nt][0]=0.f; acc[mt][nt][1]=0.f; acc[mt][nt][2]=0.f; acc[mt][nt][3]=0.f; }
    #pragma unroll
    for (int ks=0; ks<4; ++ks){
      int k0 = ks*32 + kg*8;
      bf16x8 a0, a1;
      { int r = wid*32 + l16;      a0 = *(const bf16x8*)&As[r*128 + (k0 ^ ((r&7)<<3))]; }
      { int r = wid*32 + 16 + l16; a1 = *(const bf16x8*)&As[r*128 + (k0 ^ ((r&7)<<3))]; }
      #pragma unroll
      for (int nt=0; nt<8; ++nt){
        bf16x8 b = *(const bf16x8*)&Wt[(size_t)(nt*16 + l16)*128 + k0];
        acc[0][nt] = __builtin_amdgcn_mfma_f32_16x16x32_bf16(a0, b, acc[0][nt], 0, 0, 0);
        acc[1][nt] = __builtin_amdgcn_mfma_f32_16x16x32_bf16(a1, b, acc[1][nt], 0, 0, 0);
      }
    }
    #pragma unroll
    for (int mt=0; mt<2; ++mt){
      #pragma unroll
      for (int j=0; j<4; ++j){
        int row = rowBase + wid*32 + mt*16 + kg*4 + j;
        float v[8]; float mx = 0.f;
        #pragma unroll
        for (int nt=0; nt<8; ++nt){
          float f = fmaxf(acc[mt][nt][j] + b0[net*HF + nt*16 + l16], 0.f);
          v[nt] = f; mx = fmaxf(mx, f);
        }
        #pragma unroll
        for (int off=1; off<16; off<<=1) mx = fmaxf(mx, __shfl_xor(mx, off));
        if (row < NNODES){
          float inv = (mx > 0.f) ? 255.f/mx : 0.f;
          u32 d0=0, d1=0;
          #pragma unroll
          for (int nt=0; nt<4; ++nt) d0 |= ((u32)(v[nt]*inv + 0.5f)) << (8*nt);
          #pragma unroll
          for (int nt=0; nt<4; ++nt) d1 |= ((u32)(v[4+nt]*inv + 0.5f)) << (8*nt);
          u32x2 pk; pk[0]=d0; pk[1]=d1;
          size_t off8 = (size_t)row*384 + net*128 + l16*8;
          *(u32x2*)&h8 [off8] = pk;
          *(u32x2*)&x08[off8] = pk;
          if (l16 == 0){ float s = mx * (1.f/255.f); sc[row*4 + net] = s; scx[row*4 + net] = s; }
        }
      }
    }
  }
}

// ---------------- mid GEMM: t = 0.9*agg8 + 0.1*x08 (dequant-combine in staging);
//                  h = relu((1-beta)*t + beta*(t @ cw)) -> h8/sc ----------------
__global__ __launch_bounds__(256) void gemm_mid(
    const unsigned char* __restrict__ agg8, const float* __restrict__ sca,
    const unsigned char* __restrict__ x08,  const float* __restrict__ scx,
    const short* __restrict__ W, const float beta,
    unsigned char* __restrict__ h8, float* __restrict__ sc)
{
  __shared__ short As[128*128];
  const int t = threadIdx.x;
  const int net = blockIdx.y;
  const int rowBase = blockIdx.x * 128;
  const short* Wt = W + (size_t)net*NLAYERS*HF*HF;

  #pragma unroll
  for (int it=0; it<8; ++it){
    int r = it*16 + (t>>4);
    int k = (t&15)*8;
    int gr = rowBase + r;
    bf16x8 v = {0,0,0,0,0,0,0,0};
    if (gr < NNODES){
      size_t off8 = (size_t)gr*384 + net*128 + k;
      u32x2 da = *(const u32x2*)&agg8[off8];
      u32x2 dx = *(const u32x2*)&x08[off8];
      float sa = 0.9f * sca[gr*4 + net];
      float sx = 0.1f * scx[gr*4 + net];
      #pragma unroll
      for (int j=0; j<4; ++j) v[j]   = (short)f2bf(sa*ub(da[0],j) + sx*ub(dx[0],j));
      #pragma unroll
      for (int j=0; j<4; ++j) v[4+j] = (short)f2bf(sa*ub(da[1],j) + sx*ub(dx[1],j));
    }
    *(bf16x8*)&As[r*128 + (k ^ ((r&7)<<3))] = v;
  }
  __syncthreads();

  const int wid = t>>6, lane = t&63;
  const int l16 = lane&15, kg = lane>>4;
  f32x4 acc[2][8];
  #pragma unroll
  for (int mt=0; mt<2; ++mt)
    #pragma unroll
    for (int nt=0; nt<8; ++nt){ acc[mt][nt][0]=0.f; acc[mt][nt][1]=0.f; acc[mt][nt][2]=0.f; acc[mt][nt][3]=0.f; }

  #pragma unroll
  for (int ks=0; ks<4; ++ks){
    int k0 = ks*32 + kg*8;
    bf16x8 a0, a1;
    { int r = wid*32 + l16;      a0 = *(const bf16x8*)&As[r*128 + (k0 ^ ((r&7)<<3))]; }
    { int r = wid*32 + 16 + l16; a1 = *(const bf16x8*)&As[r*128 + (k0 ^ ((r&7)<<3))]; }
    #pragma unroll
    for (int nt=0; nt<8; ++nt){
      bf16x8 b = *(const bf16x8*)&Wt[(size_t)(nt*16 + l16)*128 + k0];
      acc[0][nt] = __builtin_amdgcn_mfma_f32_16x16x32_bf16(a0, b, acc[0][nt], 0, 0, 0);
      acc[1][nt] = __builtin_amdgcn_mfma_f32_16x16x32_bf16(a1, b, acc[1][nt], 0, 0, 0);
    }
  }

  #pragma unroll
  for (int mt=0; mt<2; ++mt){
    #pragma unroll
    for (int j=0; j<4; ++j){
      int rl  = wid*32 + mt*16 + kg*4 + j;
      int row = rowBase + rl;
      float v[8]; float mx = 0.f;
      #pragma unroll
      for (int nt=0; nt<8; ++nt){
        int p = l16*8 + nt;                        // pi(col)
        float av = bf2f(As[rl*128 + (p ^ ((rl&7)<<3))]);
        float f = fmaxf((1.f-beta)*av + beta*acc[mt][nt][j], 0.f);
        v[nt] = f; mx = fmaxf(mx, f);
      }
      #pragma unroll
      for (int off=1; off<16; off<<=1) mx = fmaxf(mx, __shfl_xor(mx, off));
      if (row < NNODES){
        float inv = (mx > 0.f) ? 255.f/mx : 0.f;
        u32 d0=0, d1=0;
        #pragma unroll
        for (int nt=0; nt<4; ++nt) d0 |= ((u32)(v[nt]*inv + 0.5f)) << (8*nt);
        #pragma unroll
        for (int nt=0; nt<4; ++nt) d1 |= ((u32)(v[4+nt]*inv + 0.5f)) << (8*nt);
        u32x2 pk; pk[0]=d0; pk[1]=d1;
        *(u32x2*)&h8[(size_t)row*384 + net*128 + l16*8] = pk;
        if (l16 == 0) sc[row*4 + net] = mx * (1.f/255.f);
      }
    }
  }
}

// ---------------- output GEMM: dequant-stage h8, logits+log_softmax+ensemble mean ----------------
__global__ __launch_bounds__(256) void gemm_out(
    const unsigned char* __restrict__ h8, const float* __restrict__ sc,
    const short* __restrict__ w1t, const float* __restrict__ b1,
    float* __restrict__ out)
{
  __shared__ short As[128*128];
  const int t = threadIdx.x;
  const int rowBase = blockIdx.x * 128;
  const int wid = t>>6, lane = t&63;
  const int l16 = lane&15, kg = lane>>4;

  f32x4 sum[2][7];
  #pragma unroll
  for (int mt=0; mt<2; ++mt)
    #pragma unroll
    for (int nt=0; nt<7; ++nt){ sum[mt][nt][0]=0.f; sum[mt][nt][1]=0.f; sum[mt][nt][2]=0.f; sum[mt][nt][3]=0.f; }

  for (int net=0; net<NNETS; ++net){
    __syncthreads();
    #pragma unroll
    for (int it=0; it<8; ++it){
      int r = it*16 + (t>>4);
      int k = (t&15)*8;
      int gr = rowBase + r;
      bf16x8 v = {0,0,0,0,0,0,0,0};
      if (gr < NNODES){
        u32x2 d = *(const u32x2*)&h8[(size_t)gr*384 + net*128 + k];
        float s = sc[gr*4 + net];
        #pragma unroll
        for (int j=0; j<4; ++j) v[j]   = (short)f2bf(s * ub(d[0],j));
        #pragma unroll
        for (int j=0; j<4; ++j) v[4+j] = (short)f2bf(s * ub(d[1],j));
      }
      *(bf16x8*)&As[r*128 + (k ^ ((r&7)<<3))] = v;
    }
    __syncthreads();

    const short* Wt = w1t + (size_t)net*OUTF*HF;
    f32x4 acc[2][7];
    #pragma unroll
    for (int mt=0; mt<2; ++mt)
      #pragma unroll
      for (int nt=0; nt<7; ++nt){ acc[mt][nt][0]=0.f; acc[mt][nt][1]=0.f; acc[mt][nt][2]=0.f; acc[mt][nt][3]=0.f; }
    #pragma unroll
    for (int ks=0; ks<4; ++ks){
      int k0 = ks*32 + kg*8;
      bf16x8 a0, a1;
      { int r = wid*32 + l16;      a0 = *(const bf16x8*)&As[r*128 + (k0 ^ ((r&7)<<3))]; }
      { int r = wid*32 + 16 + l16; a1 = *(const bf16x8*)&As[r*128 + (k0 ^ ((r&7)<<3))]; }
      #pragma unroll
      for (int nt=0; nt<7; ++nt){
        bf16x8 b = *(const bf16x8*)&Wt[(size_t)(nt*16 + l16)*128 + k0];
        acc[0][nt] = __builtin_amdgcn_mfma_f32_16x16x32_bf16(a0, b, acc[0][nt], 0, 0, 0);
        acc[1][nt] = __builtin_amdgcn_mfma_f32_16x16x32_bf16(a1, b, acc[1][nt], 0, 0, 0);
      }
    }
    #pragma unroll
    for (int mt=0; mt<2; ++mt)
      #pragma unroll
      for (int nt=0; nt<7; ++nt){
        float b = b1[net*OUTF + nt*16 + l16];
        #pragma unroll
        for (int j=0; j<4; ++j) acc[mt][nt][j] += b;
      }
    #pragma unroll
    for (int mt=0; mt<2; ++mt){
      #pragma unroll
      for (int j=0; j<4; ++j){
        float m = -3.4e38f;
        #pragma unroll
        for (int nt=0; nt<7; ++nt) m = fmaxf(m, acc[mt][nt][j]);
        #pragma unroll
        for (int k=1; k<16; k<<=1) m = fmaxf(m, __shfl_xor(m, k));
        float e = 0.f;
        #pragma unroll
        for (int nt=0; nt<7; ++nt) e += expf(acc[mt][nt][j] - m);
        #pragma unroll
        for (int k=1; k<16; k<<=1) e += __shfl_xor(e, k);
        float lse = m + logf(e);
        #pragma unroll
        for (int nt=0; nt<7; ++nt) sum[mt][nt][j] += acc[mt][nt][j] - lse;
      }
    }
  }

  #pragma unroll
  for (int mt=0; mt<2; ++mt){
    #pragma unroll
    for (int nt=0; nt<7; ++nt){
      #pragma unroll
      for (int j=0; j<4; ++j){
        int row = rowBase + wid*32 + mt*16 + kg*4 + j;
        if (row < NNODES)
          __builtin_nontemporal_store(sum[mt][nt][j] * (1.f/3.f),
                                      &out[(size_t)row*OUTF + nt*16 + l16]);
      }
    }
  }
}

// ---------------- SpMM (pure gather, R12 form): agg8 = quant(A @ h8) ----------------
// one wave per node; quarter-wave per edge; 32-bit offsets; packed f32x2 FMA accumulation
__global__ __launch_bounds__(256) void spmm3(
    const int* __restrict__ row_ptr, const u32* __restrict__ meta,
    const unsigned char* __restrict__ h8, const float* __restrict__ sc,
    unsigned char* __restrict__ agg8, float* __restrict__ sca)
{
  int node = blockIdx.x*4 + (threadIdx.x>>6);
  int lane = threadIdx.x & 63;
  int q    = lane >> 4;
  int l16  = lane & 15;
  const u32 base_l = (u32)l16*8;
  int start = row_ptr[node], end = row_ptr[node+1];
  f32x2 acc[3][4];
  #pragma unroll
  for (int n=0;n<3;++n)
    #pragma unroll
    for (int p=0;p<4;++p){ acc[n][p][0]=0.f; acc[n][p][1]=0.f; }

  int e = start + q;
  for (; e + 4 < end; e += 8){
    u32 m0 = __builtin_nontemporal_load(&meta[e]);
    u32 m1 = __builtin_nontemporal_load(&meta[e+4]);
    u32 s0 = m0 & 0x1FFFFu, s1 = m1 & 0x1FFFFu;
    u32 o0 = (s0<<8) + (s0<<7) + base_l;     // s0*384 + l16*8
    u32 o1 = (s1<<8) + (s1<<7) + base_l;
    float w0 = __builtin_bit_cast(float, (m0 >> 17) << 16);
    float w1 = __builtin_bit_cast(float, (m1 >> 17) << 16);
    f32x4 c0 = *(const f32x4*)&sc[s0*4];
    f32x4 c1 = *(const f32x4*)&sc[s1*4];
    u32x2 a0 = *(const u32x2*)(h8 + o0);
    u32x2 a1 = *(const u32x2*)(h8 + o0 + 128);
    u32x2 a2 = *(const u32x2*)(h8 + o0 + 256);
    u32x2 b0 = *(const u32x2*)(h8 + o1);
    u32x2 b1 = *(const u32x2*)(h8 + o1 + 128);
    u32x2 b2 = *(const u32x2*)(h8 + o1 + 256);
    f32x2 ws00 = {w0*c0[0], w0*c0[0]}, ws01 = {w0*c0[1], w0*c0[1]}, ws02 = {w0*c0[2], w0*c0[2]};
    f32x2 ws10 = {w1*c1[0], w1*c1[0]}, ws11 = {w1*c1[1], w1*c1[1]}, ws12 = {w1*c1[2], w1*c1[2]};
    acc[0][0] += ws00*ub2(a0[0],0) + ws10*ub2(b0[0],0);
    acc[0][1] += ws00*ub2(a0[0],1) + ws10*ub2(b0[0],1);
    acc[0][2] += ws00*ub2(a0[1],0) + ws10*ub2(b0[1],0);
    acc[0][3] += ws00*ub2(a0[1],1) + ws10*ub2(b0[1],1);
    acc[1][0] += ws01*ub2(a1[0],0) + ws11*ub2(b1[0],0);
    acc[1][1] += ws01*ub2(a1[0],1) + ws11*ub2(b1[0],1);
    acc[1][2] += ws01*ub2(a1[1],0) + ws11*ub2(b1[1],0);
    acc[1][3] += ws01*ub2(a1[1],1) + ws11*ub2(b1[1],1);
    acc[2][0] += ws02*ub2(a2[0],0) + ws12*ub2(b2[0],0);
    acc[2][1] += ws02*ub2(a2[0],1) + ws12*ub2(b2[0],1);
    acc[2][2] += ws02*ub2(a2[1],0) + ws12*ub2(b2[1],0);
    acc[2][3] += ws02*ub2(a2[1],1) + ws12*ub2(b2[1],1);
  }
  for (; e < end; e += 4){
    u32 m0 = __builtin_nontemporal_load(&meta[e]);
    u32 s0 = m0 & 0x1FFFFu;
    u32 o0 = (s0<<8) + (s0<<7) + base_l;
    float w0 = __builtin_bit_cast(float, (m0 >> 17) << 16);
    f32x4 c0 = *(const f32x4*)&sc[s0*4];
    u32x2 a0 = *(const u32x2*)(h8 + o0);
    u32x2 a1 = *(const u32x2*)(h8 + o0 + 128);
    u32x2 a2 = *(const u32x2*)(h8 + o0 + 256);
    f32x2 ws00 = {w0*c0[0], w0*c0[0]}, ws01 = {w0*c0[1], w0*c0[1]}, ws02 = {w0*c0[2], w0*c0[2]};
    acc[0][0] += ws00*ub2(a0[0],0);
    acc[0][1] += ws00*ub2(a0[0],1);
    acc[0][2] += ws00*ub2(a0[1],0);
    acc[0][3] += ws00*ub2(a0[1],1);
    acc[1][0] += ws01*ub2(a1[0],0);
    acc[1][1] += ws01*ub2(a1[0],1);
    acc[1][2] += ws01*ub2(a1[1],0);
    acc[1][3] += ws01*ub2(a1[1],1);
    acc[2][0] += ws02*ub2(a2[0],0);
    acc[2][1] += ws02*ub2(a2[0],1);
    acc[2][2] += ws02*ub2(a2[1],0);
    acc[2][3] += ws02*ub2(a2[1],1);
  }
  #pragma unroll
  for (int n=0;n<3;++n)
    #pragma unroll
    for (int p=0;p<4;++p){
      acc[n][p][0] += __shfl_xor(acc[n][p][0], 16);
      acc[n][p][1] += __shfl_xor(acc[n][p][1], 16);
      acc[n][p][0] += __shfl_xor(acc[n][p][0], 32);
      acc[n][p][1] += __shfl_xor(acc[n][p][1], 32);
    }
  if (q < 3){
    float v[8];
    #pragma unroll
    for (int p=0;p<4;++p){ v[2*p] = acc[q][p][0]; v[2*p+1] = acc[q][p][1]; }
    float mx = 0.f;
    #pragma unroll
    for (int j=0;j<8;++j) mx = fmaxf(mx, v[j]);
    #pragma unroll
    for (int off=1; off<16; off<<=1) mx = fmaxf(mx, __shfl_xor(mx, off));
    float inv = (mx > 0.f) ? 255.f/mx : 0.f;
    u32 d0=0, d1=0;
    #pragma unroll
    for (int j=0;j<4;++j) d0 |= ((u32)(v[j]*inv + 0.5f)) << (8*j);
    #pragma unroll
    for (int j=0;j<4;++j) d1 |= ((u32)(v[4+j]*inv + 0.5f)) << (8*j);
    u32x2 pk; pk[0]=d0; pk[1]=d1;
    *(u32x2*)&agg8[(size_t)node*384 + q*128 + base_l] = pk;
    if (l16 == 0) sca[node*4 + q] = mx * (1.f/255.f);
  }
}

extern "C" void kernel_launch(void* const* d_in, const int* in_sizes, int n_in,
                              void* d_out, int out_size, void* d_ws, size_t ws_size,
                              hipStream_t stream){
  const float* x  = (const float*)d_in[0];
  const int*   ei = (const int*)d_in[1];
  const float* ew = (const float*)d_in[2];
  const float* w0 = (const float*)d_in[3];
  const float* b0 = (const float*)d_in[4];
  const float* w1 = (const float*)d_in[5];
  const float* b1 = (const float*)d_in[6];
  const float* cw = (const float*)d_in[7];
  float* out = (float*)d_out;

  char* ws = (char*)d_ws;
  size_t o = 0;
  auto alloc = [&](size_t b){ size_t r = o; o += (b + 255) & ~(size_t)255; return r; };
  int*   flag     = (int*)(ws + alloc(256));
  int*   counts   = (int*)(ws + alloc((size_t)NNODES*4));
  int*   scanned  = (int*)(ws + alloc((size_t)NNODES*4));
  int*   row_ptr  = (int*)(ws + alloc((size_t)(NNODES+1)*4));
  int*   partials = (int*)(ws + alloc(512*4));
  int*   rank     = (int*)(ws + alloc((size_t)NEDGES*4));
  u32*   meta     = (u32*)(ws + alloc((size_t)NEDGES*4));
  short* w0t = (short*)(ws + alloc((size_t)NNETS*HF*HF*2));
  short* cwt = (short*)(ws + alloc((size_t)NNETS*NLAYERS*HF*HF*2));
  short* w1t = (short*)(ws + alloc((size_t)NNETS*OUTF*HF*2));
  unsigned char* h8   = (unsigned char*)(ws + alloc((size_t)NNODES*NNETS*128));
  float* sc  = (float*)(ws + alloc((size_t)NNODES*4*4));
  unsigned char* x08  = (unsigned char*)(ws + alloc((size_t)NNODES*NNETS*128));
  float* scx = (float*)(ws + alloc((size_t)NNODES*4*4));
  unsigned char* agg8 = (unsigned char*)(ws + alloc((size_t)NNODES*NNETS*128));
  float* sca = (float*)(ws + alloc((size_t)NNODES*4*4));
  (void)ws_size; (void)in_sizes; (void)n_in; (void)out_size;
  // total ws use ~137 MB

  hipMemsetAsync(counts, 0, (size_t)NNODES*4, stream);
  detect_fmt    <<<1,   64,  0, stream>>>((const u64*)ei, flag);
  hist_kernel   <<<6250,256, 0, stream>>>(ei, flag, counts, rank);
  scan1         <<<391, 256, 0, stream>>>(counts, scanned, partials);
  scan2         <<<1,   512, 0, stream>>>(partials, 391);
  scan3         <<<391, 256, 0, stream>>>(scanned, partials, row_ptr);
  scatter_kernel<<<6250,256, 0, stream>>>(ei, ew, flag, row_ptr, rank, meta);

  prep_w<<<1128, 256, 0, stream>>>(w0, cw, w1, w0t, cwt, w1t);

  gemm_in<<<782, 256, 0, stream>>>(x, w0t, b0, h8, sc, x08, scx);
  for (int l=0; l<NLAYERS; ++l){
    float beta = logf(0.5f/(float)(l+1) + 1.0f);
    spmm3<<<25000, 256, 0, stream>>>(row_ptr, meta, h8, sc, agg8, sca);
    gemm_mid<<<dim3(782,3), 256, 0, stream>>>(agg8, sca, x08, scx,
                                              cwt + (size_t)l*HF*HF, beta, h8, sc);
  }
  gemm_out<<<782, 256, 0, stream>>>(h8, sc, w1t, b1, out);
}

// Round 15
// 1110.575 us; speedup vs baseline: 1.1773x; 1.0753x over previous
//
#include <hip/hip_runtime.h>
#include <hip/hip_bf16.h>

#define NNODES 100000
#define NEDGES 1600000
#define INF_   128
#define HF     128
#define OUTF   112
#define NLAYERS 4
#define NNETS  3

typedef __attribute__((ext_vector_type(8))) short bf16x8;
typedef __attribute__((ext_vector_type(8))) unsigned short u16x8;
typedef __attribute__((ext_vector_type(4))) float f32x4;
typedef __attribute__((ext_vector_type(2))) float f32x2;
typedef __attribute__((ext_vector_type(2))) unsigned int u32x2;
typedef unsigned long long u64;
typedef unsigned int u32;

__device__ __forceinline__ float bf2f(short u){
  unsigned x = ((unsigned)(unsigned short)u) << 16;
  return __builtin_bit_cast(float, x);
}
__device__ __forceinline__ unsigned short f2bf(float f){
  unsigned u = __builtin_bit_cast(unsigned, f);
  u += 0x7fffu + ((u >> 16) & 1u);   // RNE
  return (unsigned short)(u >> 16);
}
__device__ __forceinline__ float ub(u32 q, int j){ return (float)((q >> (8*j)) & 0xFF); }

// 4 int8 MACs in 6 instrs: 4x v_cvt_f32_ubyteN + 2x v_pk_fma_f32.
// pa += ws * {byte0,byte1}; pb += ws * {byte2,byte3}
__device__ __forceinline__ void mac4(f32x2& pa, f32x2& pb, f32x2 ws, u32 q){
  asm volatile(
    "v_cvt_f32_ubyte0 v20, %3\n\t"
    "v_cvt_f32_ubyte1 v21, %3\n\t"
    "v_cvt_f32_ubyte2 v22, %3\n\t"
    "v_cvt_f32_ubyte3 v23, %3\n\t"
    "v_pk_fma_f32 %0, %2, v[20:21], %0\n\t"
    "v_pk_fma_f32 %1, %2, v[22:23], %1"
    : "+v"(pa), "+v"(pb)
    : "v"(ws), "v"(q)
    : "v20","v21","v22","v23");
}

// hidden-feature permutation: canonical col c -> stored position p = (c&15)*8 + (c>>4)

// ---------------- int64-vs-int32 edge_index format probe ----------------
__global__ void detect_fmt(const u64* __restrict__ ei64, int* __restrict__ flag){
  u64 v = ei64[threadIdx.x];
  u64 b = __ballot((v >> 32) != 0ull);
  if (threadIdx.x == 0) flag[0] = (b == 0ull) ? 1 : 0;
}

__device__ __forceinline__ int load_dst(const int* ei, int is64, int e){
  return is64 ? ei[2*(NEDGES + e)] : ei[NEDGES + e];
}
__device__ __forceinline__ int load_src(const int* ei, int is64, int e){
  return is64 ? ei[2*e] : ei[e];
}

// ---------------- CSR build (de-atomic scatter) ----------------
__global__ void hist_kernel(const int* __restrict__ ei, const int* __restrict__ flag,
                            int* counts, int* __restrict__ rank){
  int e = blockIdx.x*256 + threadIdx.x;
  if (e < NEDGES){
    int d = load_dst(ei, flag[0], e);
    if ((unsigned)d < NNODES) rank[e] = atomicAdd(&counts[d], 1);
  }
}

__global__ __launch_bounds__(256) void scan1(const int* __restrict__ counts,
                                             int* __restrict__ scanned,
                                             int* __restrict__ partials){
  __shared__ int s[256];
  int t = threadIdx.x, i = blockIdx.x*256 + t;
  int v = (i < NNODES) ? counts[i] : 0;
  s[t] = v; __syncthreads();
  for (int off=1; off<256; off<<=1){
    int a = (t >= off) ? s[t-off] : 0;
    __syncthreads();
    s[t] += a;
    __syncthreads();
  }
  if (i < NNODES) scanned[i] = s[t] - v;
  if (t == 255) partials[blockIdx.x] = s[255];
}

__global__ __launch_bounds__(512) void scan2(int* partials, int G){
  __shared__ int s[512];
  int t = threadIdx.x;
  int v = (t < G) ? partials[t] : 0;
  s[t] = v; __syncthreads();
  for (int off=1; off<512; off<<=1){
    int a = (t >= off) ? s[t-off] : 0;
    __syncthreads();
    s[t] += a;
    __syncthreads();
  }
  if (t < G) partials[t] = s[t] - v;
}

__global__ void scan3(const int* __restrict__ scanned, const int* __restrict__ partials,
                      int* __restrict__ row_ptr){
  int i = blockIdx.x*256 + threadIdx.x;
  if (i < NNODES){
    row_ptr[i] = scanned[i] + partials[i>>8];
  } else if (i == NNODES){
    row_ptr[NNODES] = NEDGES;
  }
}

// positional scatter: pos = row_ptr[dst] + rank[e]  (no atomics)
// packed meta: bits[16:0]=src, bits[31:17]=weight as sign-less bf16
__global__ void scatter_kernel(const int* __restrict__ ei, const float* __restrict__ ew,
                               const int* __restrict__ flag,
                               const int* __restrict__ row_ptr, const int* __restrict__ rank,
                               u32* __restrict__ meta){
  int e = blockIdx.x*256 + threadIdx.x;
  if (e < NEDGES){
    int is64 = flag[0];
    int s = load_src(ei, is64, e);
    int d = load_dst(ei, is64, e);
    float w = __builtin_nontemporal_load(&ew[e]);
    if ((unsigned)d < NNODES && (unsigned)s < NNODES){
      int pos = row_ptr[d] + rank[e];
      if ((unsigned)pos < NEDGES){
        u32 wb = __builtin_bit_cast(u32, w);
        u32 w15 = ((wb + 0x8000u) >> 16) & 0x7FFFu;
        __builtin_nontemporal_store((w15 << 17) | (u32)s, &meta[pos]);
      }
    }
  }
}

// ---------------- weight prep (fp32 -> bf16, transposed; cwt/w1t K pre-permuted by pi^-1) ----------------
__global__ void prep_w(const float* __restrict__ w0, const float* __restrict__ cw,
                       const float* __restrict__ w1,
                       short* __restrict__ w0t, short* __restrict__ cwt, short* __restrict__ w1t){
  int i = blockIdx.x*256 + threadIdx.x;
  const int n0 = NNETS*HF*HF;
  const int n1 = NNETS*NLAYERS*HF*HF;
  const int n2 = NNETS*OUTF*HF;
  if (i < n0){
    int net = i/(HF*HF), r = i%(HF*HF), c = r/HF, k = r%HF;
    w0t[i] = (short)f2bf(w0[(size_t)net*HF*HF + k*HF + c]);
  } else if (i < n0 + n1){
    int j = i - n0;
    int nl = j/(HF*HF), r = j%(HF*HF), c = r/HF, kp = r%HF;
    int k = ((kp&7)<<4) | (kp>>3);                 // pi^-1
    cwt[j] = (short)f2bf(cw[(size_t)nl*HF*HF + k*HF + c]);
  } else if (i < n0 + n1 + n2){
    int j = i - n0 - n1;
    int net = j/(OUTF*HF), r = j%(OUTF*HF), c = r/HF, kp = r%HF;
    int k = ((kp&7)<<4) | (kp>>3);                 // pi^-1
    w1t[j] = (short)f2bf(w1[(size_t)net*HF*OUTF + k*OUTF + c]);
  }
}

// ---------------- input GEMM: h0 = relu(x @ w0 + b0) -> h8/sc AND x08/scx (identical) ----------------
__global__ __launch_bounds__(256) void gemm_in(
    const float* __restrict__ x, const short* __restrict__ w0t, const float* __restrict__ b0,
    unsigned char* __restrict__ h8, float* __restrict__ sc,
    unsigned char* __restrict__ x08, float* __restrict__ scx)
{
  __shared__ short As[128*128];
  const int t = threadIdx.x;
  const int rowBase = blockIdx.x * 128;
  #pragma unroll
  for (int it=0; it<8; ++it){
    int r = it*16 + (t>>4);
    int k = (t&15)*8;
    int gr = rowBase + r;
    bf16x8 v = {0,0,0,0,0,0,0,0};
    if (gr < NNODES){
      f32x4 f0 = __builtin_nontemporal_load((const f32x4*)&x[(size_t)gr*128 + k]);
      f32x4 f1 = __builtin_nontemporal_load((const f32x4*)&x[(size_t)gr*128 + k + 4]);
      v[0]=(short)f2bf(f0[0]); v[1]=(short)f2bf(f0[1]); v[2]=(short)f2bf(f0[2]); v[3]=(short)f2bf(f0[3]);
      v[4]=(short)f2bf(f1[0]); v[5]=(short)f2bf(f1[1]); v[6]=(short)f2bf(f1[2]); v[7]=(short)f2bf(f1[3]);
    }
    *(bf16x8*)&As[r*128 + (k ^ ((r&7)<<3))] = v;
  }
  __syncthreads();

  const int wid = t>>6, lane = t&63;
  const int l16 = lane&15, kg = lane>>4;
  for (int net=0; net<NNETS; ++net){
    const short* Wt = w0t + (size_t)net*HF*HF;
    f32x4 acc[2][8];
    #pragma unroll
    for (int mt=0; mt<2; ++mt)
      #pragma unroll
      for (int nt=0; nt<8; ++nt){ acc[mt][nt][0]=0.f; acc[mt][nt][1]=0.f; acc[mt][nt][2]=0.f; acc[mt][nt][3]=0.f; }
    #pragma unroll
    for (int ks=0; ks<4; ++ks){
      int k0 = ks*32 + kg*8;
      bf16x8 a0, a1;
      { int r = wid*32 + l16;      a0 = *(const bf16x8*)&As[r*128 + (k0 ^ ((r&7)<<3))]; }
      { int r = wid*32 + 16 + l16; a1 = *(const bf16x8*)&As[r*128 + (k0 ^ ((r&7)<<3))]; }
      #pragma unroll
      for (int nt=0; nt<8; ++nt){
        bf16x8 b = *(const bf16x8*)&Wt[(size_t)(nt*16 + l16)*128 + k0];
        acc[0][nt] = __builtin_amdgcn_mfma_f32_16x16x32_bf16(a0, b, acc[0][nt], 0, 0, 0);
        acc[1][nt] = __builtin_amdgcn_mfma_f32_16x16x32_bf16(a1, b, acc[1][nt], 0, 0, 0);
      }
    }
    #pragma unroll
    for (int mt=0; mt<2; ++mt){
      #pragma unroll
      for (int j=0; j<4; ++j){
        int row = rowBase + wid*32 + mt*16 + kg*4 + j;
        float v[8]; float mx = 0.f;
        #pragma unroll
        for (int nt=0; nt<8; ++nt){
          float f = fmaxf(acc[mt][nt][j] + b0[net*HF + nt*16 + l16], 0.f);
          v[nt] = f; mx = fmaxf(mx, f);
        }
        #pragma unroll
        for (int off=1; off<16; off<<=1) mx = fmaxf(mx, __shfl_xor(mx, off));
        if (row < NNODES){
          float inv = (mx > 0.f) ? 255.f/mx : 0.f;
          u32 d0=0, d1=0;
          #pragma unroll
          for (int nt=0; nt<4; ++nt) d0 |= ((u32)(v[nt]*inv + 0.5f)) << (8*nt);
          #pragma unroll
          for (int nt=0; nt<4; ++nt) d1 |= ((u32)(v[4+nt]*inv + 0.5f)) << (8*nt);
          u32x2 pk; pk[0]=d0; pk[1]=d1;
          size_t off8 = (size_t)row*384 + net*128 + l16*8;
          *(u32x2*)&h8 [off8] = pk;
          *(u32x2*)&x08[off8] = pk;
          if (l16 == 0){ float s = mx * (1.f/255.f); sc[row*4 + net] = s; scx[row*4 + net] = s; }
        }
      }
    }
  }
}

// ---------------- mid GEMM: t = 0.9*agg8 + 0.1*x08 (dequant-combine in staging);
//                  h = relu((1-beta)*t + beta*(t @ cw)) -> h8/sc ----------------
__global__ __launch_bounds__(256) void gemm_mid(
    const unsigned char* __restrict__ agg8, const float* __restrict__ sca,
    const unsigned char* __restrict__ x08,  const float* __restrict__ scx,
    const short* __restrict__ W, const float beta,
    unsigned char* __restrict__ h8, float* __restrict__ sc)
{
  __shared__ short As[128*128];
  const int t = threadIdx.x;
  const int net = blockIdx.y;
  const int rowBase = blockIdx.x * 128;
  const short* Wt = W + (size_t)net*NLAYERS*HF*HF;

  #pragma unroll
  for (int it=0; it<8; ++it){
    int r = it*16 + (t>>4);
    int k = (t&15)*8;
    int gr = rowBase + r;
    bf16x8 v = {0,0,0,0,0,0,0,0};
    if (gr < NNODES){
      size_t off8 = (size_t)gr*384 + net*128 + k;
      u32x2 da = *(const u32x2*)&agg8[off8];
      u32x2 dx = *(const u32x2*)&x08[off8];
      float sa = 0.9f * sca[gr*4 + net];
      float sx = 0.1f * scx[gr*4 + net];
      #pragma unroll
      for (int j=0; j<4; ++j) v[j]   = (short)f2bf(sa*ub(da[0],j) + sx*ub(dx[0],j));
      #pragma unroll
      for (int j=0; j<4; ++j) v[4+j] = (short)f2bf(sa*ub(da[1],j) + sx*ub(dx[1],j));
    }
    *(bf16x8*)&As[r*128 + (k ^ ((r&7)<<3))] = v;
  }
  __syncthreads();

  const int wid = t>>6, lane = t&63;
  const int l16 = lane&15, kg = lane>>4;
  f32x4 acc[2][8];
  #pragma unroll
  for (int mt=0; mt<2; ++mt)
    #pragma unroll
    for (int nt=0; nt<8; ++nt){ acc[mt][nt][0]=0.f; acc[mt][nt][1]=0.f; acc[mt][nt][2]=0.f; acc[mt][nt][3]=0.f; }

  #pragma unroll
  for (int ks=0; ks<4; ++ks){
    int k0 = ks*32 + kg*8;
    bf16x8 a0, a1;
    { int r = wid*32 + l16;      a0 = *(const bf16x8*)&As[r*128 + (k0 ^ ((r&7)<<3))]; }
    { int r = wid*32 + 16 + l16; a1 = *(const bf16x8*)&As[r*128 + (k0 ^ ((r&7)<<3))]; }
    #pragma unroll
    for (int nt=0; nt<8; ++nt){
      bf16x8 b = *(const bf16x8*)&Wt[(size_t)(nt*16 + l16)*128 + k0];
      acc[0][nt] = __builtin_amdgcn_mfma_f32_16x16x32_bf16(a0, b, acc[0][nt], 0, 0, 0);
      acc[1][nt] = __builtin_amdgcn_mfma_f32_16x16x32_bf16(a1, b, acc[1][nt], 0, 0, 0);
    }
  }

  #pragma unroll
  for (int mt=0; mt<2; ++mt){
    #pragma unroll
    for (int j=0; j<4; ++j){
      int rl  = wid*32 + mt*16 + kg*4 + j;
      int row = rowBase + rl;
      float v[8]; float mx = 0.f;
      #pragma unroll
      for (int nt=0; nt<8; ++nt){
        int p = l16*8 + nt;                        // pi(col)
        float av = bf2f(As[rl*128 + (p ^ ((rl&7)<<3))]);
        float f = fmaxf((1.f-beta)*av + beta*acc[mt][nt][j], 0.f);
        v[nt] = f; mx = fmaxf(mx, f);
      }
      #pragma unroll
      for (int off=1; off<16; off<<=1) mx = fmaxf(mx, __shfl_xor(mx, off));
      if (row < NNODES){
        float inv = (mx > 0.f) ? 255.f/mx : 0.f;
        u32 d0=0, d1=0;
        #pragma unroll
        for (int nt=0; nt<4; ++nt) d0 |= ((u32)(v[nt]*inv + 0.5f)) << (8*nt);
        #pragma unroll
        for (int nt=0; nt<4; ++nt) d1 |= ((u32)(v[4+nt]*inv + 0.5f)) << (8*nt);
        u32x2 pk; pk[0]=d0; pk[1]=d1;
        *(u32x2*)&h8[(size_t)row*384 + net*128 + l16*8] = pk;
        if (l16 == 0) sc[row*4 + net] = mx * (1.f/255.f);
      }
    }
  }
}

// ---------------- output GEMM: dequant-stage h8, logits+log_softmax+ensemble mean ----------------
__global__ __launch_bounds__(256) void gemm_out(
    const unsigned char* __restrict__ h8, const float* __restrict__ sc,
    const short* __restrict__ w1t, const float* __restrict__ b1,
    float* __restrict__ out)
{
  __shared__ short As[128*128];
  const int t = threadIdx.x;
  const int rowBase = blockIdx.x * 128;
  const int wid = t>>6, lane = t&63;
  const int l16 = lane&15, kg = lane>>4;

  f32x4 sum[2][7];
  #pragma unroll
  for (int mt=0; mt<2; ++mt)
    #pragma unroll
    for (int nt=0; nt<7; ++nt){ sum[mt][nt][0]=0.f; sum[mt][nt][1]=0.f; sum[mt][nt][2]=0.f; sum[mt][nt][3]=0.f; }

  for (int net=0; net<NNETS; ++net){
    __syncthreads();
    #pragma unroll
    for (int it=0; it<8; ++it){
      int r = it*16 + (t>>4);
      int k = (t&15)*8;
      int gr = rowBase + r;
      bf16x8 v = {0,0,0,0,0,0,0,0};
      if (gr < NNODES){
        u32x2 d = *(const u32x2*)&h8[(size_t)gr*384 + net*128 + k];
        float s = sc[gr*4 + net];
        #pragma unroll
        for (int j=0; j<4; ++j) v[j]   = (short)f2bf(s * ub(d[0],j));
        #pragma unroll
        for (int j=0; j<4; ++j) v[4+j] = (short)f2bf(s * ub(d[1],j));
      }
      *(bf16x8*)&As[r*128 + (k ^ ((r&7)<<3))] = v;
    }
    __syncthreads();

    const short* Wt = w1t + (size_t)net*OUTF*HF;
    f32x4 acc[2][7];
    #pragma unroll
    for (int mt=0; mt<2; ++mt)
      #pragma unroll
      for (int nt=0; nt<7; ++nt){ acc[mt][nt][0]=0.f; acc[mt][nt][1]=0.f; acc[mt][nt][2]=0.f; acc[mt][nt][3]=0.f; }
    #pragma unroll
    for (int ks=0; ks<4; ++ks){
      int k0 = ks*32 + kg*8;
      bf16x8 a0, a1;
      { int r = wid*32 + l16;      a0 = *(const bf16x8*)&As[r*128 + (k0 ^ ((r&7)<<3))]; }
      { int r = wid*32 + 16 + l16; a1 = *(const bf16x8*)&As[r*128 + (k0 ^ ((r&7)<<3))]; }
      #pragma unroll
      for (int nt=0; nt<7; ++nt){
        bf16x8 b = *(const bf16x8*)&Wt[(size_t)(nt*16 + l16)*128 + k0];
        acc[0][nt] = __builtin_amdgcn_mfma_f32_16x16x32_bf16(a0, b, acc[0][nt], 0, 0, 0);
        acc[1][nt] = __builtin_amdgcn_mfma_f32_16x16x32_bf16(a1, b, acc[1][nt], 0, 0, 0);
      }
    }
    #pragma unroll
    for (int mt=0; mt<2; ++mt)
      #pragma unroll
      for (int nt=0; nt<7; ++nt){
        float b = b1[net*OUTF + nt*16 + l16];
        #pragma unroll
        for (int j=0; j<4; ++j) acc[mt][nt][j] += b;
      }
    #pragma unroll
    for (int mt=0; mt<2; ++mt){
      #pragma unroll
      for (int j=0; j<4; ++j){
        float m = -3.4e38f;
        #pragma unroll
        for (int nt=0; nt<7; ++nt) m = fmaxf(m, acc[mt][nt][j]);
        #pragma unroll
        for (int k=1; k<16; k<<=1) m = fmaxf(m, __shfl_xor(m, k));
        float e = 0.f;
        #pragma unroll
        for (int nt=0; nt<7; ++nt) e += expf(acc[mt][nt][j] - m);
        #pragma unroll
        for (int k=1; k<16; k<<=1) e += __shfl_xor(e, k);
        float lse = m + logf(e);
        #pragma unroll
        for (int nt=0; nt<7; ++nt) sum[mt][nt][j] += acc[mt][nt][j] - lse;
      }
    }
  }

  #pragma unroll
  for (int mt=0; mt<2; ++mt){
    #pragma unroll
    for (int nt=0; nt<7; ++nt){
      #pragma unroll
      for (int j=0; j<4; ++j){
        int row = rowBase + wid*32 + mt*16 + kg*4 + j;
        if (row < NNODES)
          __builtin_nontemporal_store(sum[mt][nt][j] * (1.f/3.f),
                                      &out[(size_t)row*OUTF + nt*16 + l16]);
      }
    }
  }
}

// ---------------- SpMM (pure gather, asm-minimal VALU): agg8 = quant(A @ h8) ----------------
// one wave per node; quarter-wave per edge; cvt_f32_ubyteN + v_pk_fma_f32 core
__global__ __launch_bounds__(256) void spmm3(
    const int* __restrict__ row_ptr, const u32* __restrict__ meta,
    const unsigned char* __restrict__ h8, const float* __restrict__ sc,
    unsigned char* __restrict__ agg8, float* __restrict__ sca)
{
  int node = blockIdx.x*4 + (threadIdx.x>>6);
  int lane = threadIdx.x & 63;
  int q    = lane >> 4;
  int l16  = lane & 15;
  const u32 base_l = (u32)l16*8;
  int start = row_ptr[node], end = row_ptr[node+1];
  f32x2 acc[3][4];
  #pragma unroll
  for (int n=0;n<3;++n)
    #pragma unroll
    for (int p=0;p<4;++p){ acc[n][p][0]=0.f; acc[n][p][1]=0.f; }

  int e = start + q;
  for (; e + 4 < end; e += 8){
    u32 m0 = __builtin_nontemporal_load(&meta[e]);
    u32 m1 = __builtin_nontemporal_load(&meta[e+4]);
    u32 s0 = m0 & 0x1FFFFu, s1 = m1 & 0x1FFFFu;
    u32 o0 = (s0<<8) + (s0<<7) + base_l;     // s0*384 + l16*8
    u32 o1 = (s1<<8) + (s1<<7) + base_l;
    float w0 = __builtin_bit_cast(float, (m0 >> 17) << 16);
    float w1 = __builtin_bit_cast(float, (m1 >> 17) << 16);
    f32x4 c0 = *(const f32x4*)&sc[s0*4];
    f32x4 c1 = *(const f32x4*)&sc[s1*4];
    u32x2 a0 = *(const u32x2*)(h8 + o0);
    u32x2 a1 = *(const u32x2*)(h8 + o0 + 128);
    u32x2 a2 = *(const u32x2*)(h8 + o0 + 256);
    u32x2 b0 = *(const u32x2*)(h8 + o1);
    u32x2 b1 = *(const u32x2*)(h8 + o1 + 128);
    u32x2 b2 = *(const u32x2*)(h8 + o1 + 256);
    f32x2 W00 = {w0*c0[0], w0*c0[0]}, W01 = {w0*c0[1], w0*c0[1]}, W02 = {w0*c0[2], w0*c0[2]};
    f32x2 W10 = {w1*c1[0], w1*c1[0]}, W11 = {w1*c1[1], w1*c1[1]}, W12 = {w1*c1[2], w1*c1[2]};
    mac4(acc[0][0], acc[0][1], W00, a0[0]);
    mac4(acc[0][2], acc[0][3], W00, a0[1]);
    mac4(acc[1][0], acc[1][1], W01, a1[0]);
    mac4(acc[1][2], acc[1][3], W01, a1[1]);
    mac4(acc[2][0], acc[2][1], W02, a2[0]);
    mac4(acc[2][2], acc[2][3], W02, a2[1]);
    mac4(acc[0][0], acc[0][1], W10, b0[0]);
    mac4(acc[0][2], acc[0][3], W10, b0[1]);
    mac4(acc[1][0], acc[1][1], W11, b1[0]);
    mac4(acc[1][2], acc[1][3], W11, b1[1]);
    mac4(acc[2][0], acc[2][1], W12, b2[0]);
    mac4(acc[2][2], acc[2][3], W12, b2[1]);
  }
  for (; e < end; e += 4){
    u32 m0 = __builtin_nontemporal_load(&meta[e]);
    u32 s0 = m0 & 0x1FFFFu;
    u32 o0 = (s0<<8) + (s0<<7) + base_l;
    float w0 = __builtin_bit_cast(float, (m0 >> 17) << 16);
    f32x4 c0 = *(const f32x4*)&sc[s0*4];
    u32x2 a0 = *(const u32x2*)(h8 + o0);
    u32x2 a1 = *(const u32x2*)(h8 + o0 + 128);
    u32x2 a2 = *(const u32x2*)(h8 + o0 + 256);
    f32x2 W00 = {w0*c0[0], w0*c0[0]}, W01 = {w0*c0[1], w0*c0[1]}, W02 = {w0*c0[2], w0*c0[2]};
    mac4(acc[0][0], acc[0][1], W00, a0[0]);
    mac4(acc[0][2], acc[0][3], W00, a0[1]);
    mac4(acc[1][0], acc[1][1], W01, a1[0]);
    mac4(acc[1][2], acc[1][3], W01, a1[1]);
    mac4(acc[2][0], acc[2][1], W02, a2[0]);
    mac4(acc[2][2], acc[2][3], W02, a2[1]);
  }
  #pragma unroll
  for (int n=0;n<3;++n)
    #pragma unroll
    for (int p=0;p<4;++p){
      acc[n][p][0] += __shfl_xor(acc[n][p][0], 16);
      acc[n][p][1] += __shfl_xor(acc[n][p][1], 16);
      acc[n][p][0] += __shfl_xor(acc[n][p][0], 32);
      acc[n][p][1] += __shfl_xor(acc[n][p][1], 32);
    }
  if (q < 3){
    float v[8];
    #pragma unroll
    for (int p=0;p<4;++p){ v[2*p] = acc[q][p][0]; v[2*p+1] = acc[q][p][1]; }
    float mx = 0.f;
    #pragma unroll
    for (int j=0;j<8;++j) mx = fmaxf(mx, v[j]);
    #pragma unroll
    for (int off=1; off<16; off<<=1) mx = fmaxf(mx, __shfl_xor(mx, off));
    float inv = (mx > 0.f) ? 255.f/mx : 0.f;
    u32 d0=0, d1=0;
    #pragma unroll
    for (int j=0;j<4;++j) d0 |= ((u32)(v[j]*inv + 0.5f)) << (8*j);
    #pragma unroll
    for (int j=0;j<4;++j) d1 |= ((u32)(v[4+j]*inv + 0.5f)) << (8*j);
    u32x2 pk; pk[0]=d0; pk[1]=d1;
    *(u32x2*)&agg8[(size_t)node*384 + q*128 + base_l] = pk;
    if (l16 == 0) sca[node*4 + q] = mx * (1.f/255.f);
  }
}

extern "C" void kernel_launch(void* const* d_in, const int* in_sizes, int n_in,
                              void* d_out, int out_size, void* d_ws, size_t ws_size,
                              hipStream_t stream){
  const float* x  = (const float*)d_in[0];
  const int*   ei = (const int*)d_in[1];
  const float* ew = (const float*)d_in[2];
  const float* w0 = (const float*)d_in[3];
  const float* b0 = (const float*)d_in[4];
  const float* w1 = (const float*)d_in[5];
  const float* b1 = (const float*)d_in[6];
  const float* cw = (const float*)d_in[7];
  float* out = (float*)d_out;

  char* ws = (char*)d_ws;
  size_t o = 0;
  auto alloc = [&](size_t b){ size_t r = o; o += (b + 255) & ~(size_t)255; return r; };
  int*   flag     = (int*)(ws + alloc(256));
  int*   counts   = (int*)(ws + alloc((size_t)NNODES*4));
  int*   scanned  = (int*)(ws + alloc((size_t)NNODES*4));
  int*   row_ptr  = (int*)(ws + alloc((size_t)(NNODES+1)*4));
  int*   partials = (int*)(ws + alloc(512*4));
  int*   rank     = (int*)(ws + alloc((size_t)NEDGES*4));
  u32*   meta     = (u32*)(ws + alloc((size_t)NEDGES*4));
  short* w0t = (short*)(ws + alloc((size_t)NNETS*HF*HF*2));
  short* cwt = (short*)(ws + alloc((size_t)NNETS*NLAYERS*HF*HF*2));
  short* w1t = (short*)(ws + alloc((size_t)NNETS*OUTF*HF*2));
  unsigned char* h8   = (unsigned char*)(ws + alloc((size_t)NNODES*NNETS*128));
  float* sc  = (float*)(ws + alloc((size_t)NNODES*4*4));
  unsigned char* x08  = (unsigned char*)(ws + alloc((size_t)NNODES*NNETS*128));
  float* scx = (float*)(ws + alloc((size_t)NNODES*4*4));
  unsigned char* agg8 = (unsigned char*)(ws + alloc((size_t)NNODES*NNETS*128));
  float* sca = (float*)(ws + alloc((size_t)NNODES*4*4));
  (void)ws_size; (void)in_sizes; (void)n_in; (void)out_size;
  // total ws use ~137 MB

  hipMemsetAsync(counts, 0, (size_t)NNODES*4, stream);
  detect_fmt    <<<1,   64,  0, stream>>>((const u64*)ei, flag);
  hist_kernel   <<<6250,256, 0, stream>>>(ei, flag, counts, rank);
  scan1         <<<391, 256, 0, stream>>>(counts, scanned, partials);
  scan2         <<<1,   512, 0, stream>>>(partials, 391);
  scan3         <<<391, 256, 0, stream>>>(scanned, partials, row_ptr);
  scatter_kernel<<<6250,256, 0, stream>>>(ei, ew, flag, row_ptr, rank, meta);

  prep_w<<<1128, 256, 0, stream>>>(w0, cw, w1, w0t, cwt, w1t);

  gemm_in<<<782, 256, 0, stream>>>(x, w0t, b0, h8, sc, x08, scx);
  for (int l=0; l<NLAYERS; ++l){
    float beta = logf(0.5f/(float)(l+1) + 1.0f);
    spmm3<<<25000, 256, 0, stream>>>(row_ptr, meta, h8, sc, agg8, sca);
    gemm_mid<<<dim3(782,3), 256, 0, stream>>>(agg8, sca, x08, scx,
                                              cwt + (size_t)l*HF*HF, beta, h8, sc);
  }
  gemm_out<<<782, 256, 0, stream>>>(h8, sc, w1t, b1, out);
}

// Round 16
// 1101.846 us; speedup vs baseline: 1.1866x; 1.0079x over previous
//
#include <hip/hip_runtime.h>
#include <hip/hip_bf16.h>

#define NNODES 100000
#define NEDGES 1600000
#define INF_   128
#define HF     128
#define OUTF   112
#define NLAYERS 4
#define NNETS  3

typedef __attribute__((ext_vector_type(8))) short bf16x8;
typedef __attribute__((ext_vector_type(8))) unsigned short u16x8;
typedef __attribute__((ext_vector_type(4))) float f32x4;
typedef __attribute__((ext_vector_type(2))) float f32x2;
typedef __attribute__((ext_vector_type(2))) unsigned int u32x2;
typedef unsigned long long u64;
typedef unsigned int u32;

__device__ __forceinline__ float bf2f(short u){
  unsigned x = ((unsigned)(unsigned short)u) << 16;
  return __builtin_bit_cast(float, x);
}
__device__ __forceinline__ unsigned short f2bf(float f){
  unsigned u = __builtin_bit_cast(unsigned, f);
  u += 0x7fffu + ((u >> 16) & 1u);   // RNE
  return (unsigned short)(u >> 16);
}
__device__ __forceinline__ float ub(u32 q, int j){ return (float)((q >> (8*j)) & 0xFF); }

// 4 int8 MACs in 6 instrs: 4x v_cvt_f32_ubyteN + 2x v_pk_fma_f32.
// pa += ws * {byte0,byte1}; pb += ws * {byte2,byte3}
__device__ __forceinline__ void mac4(f32x2& pa, f32x2& pb, f32x2 ws, u32 q){
  asm volatile(
    "v_cvt_f32_ubyte0 v20, %3\n\t"
    "v_cvt_f32_ubyte1 v21, %3\n\t"
    "v_cvt_f32_ubyte2 v22, %3\n\t"
    "v_cvt_f32_ubyte3 v23, %3\n\t"
    "v_pk_fma_f32 %0, %2, v[20:21], %0\n\t"
    "v_pk_fma_f32 %1, %2, v[22:23], %1"
    : "+v"(pa), "+v"(pb)
    : "v"(ws), "v"(q)
    : "v20","v21","v22","v23");
}

// hidden-feature permutation: canonical col c -> stored position p = (c&15)*8 + (c>>4)

// ---------------- int64-vs-int32 edge_index format probe ----------------
__global__ void detect_fmt(const u64* __restrict__ ei64, int* __restrict__ flag){
  u64 v = ei64[threadIdx.x];
  u64 b = __ballot((v >> 32) != 0ull);
  if (threadIdx.x == 0) flag[0] = (b == 0ull) ? 1 : 0;
}

__device__ __forceinline__ int load_dst(const int* ei, int is64, int e){
  return is64 ? ei[2*(NEDGES + e)] : ei[NEDGES + e];
}
__device__ __forceinline__ int load_src(const int* ei, int is64, int e){
  return is64 ? ei[2*e] : ei[e];
}

// ---------------- CSR build (de-atomic scatter) ----------------
__global__ void hist_kernel(const int* __restrict__ ei, const int* __restrict__ flag,
                            int* counts, int* __restrict__ rank){
  int e = blockIdx.x*256 + threadIdx.x;
  if (e < NEDGES){
    int d = load_dst(ei, flag[0], e);
    if ((unsigned)d < NNODES) rank[e] = atomicAdd(&counts[d], 1);
  }
}

__global__ __launch_bounds__(256) void scan1(const int* __restrict__ counts,
                                             int* __restrict__ scanned,
                                             int* __restrict__ partials){
  __shared__ int s[256];
  int t = threadIdx.x, i = blockIdx.x*256 + t;
  int v = (i < NNODES) ? counts[i] : 0;
  s[t] = v; __syncthreads();
  for (int off=1; off<256; off<<=1){
    int a = (t >= off) ? s[t-off] : 0;
    __syncthreads();
    s[t] += a;
    __syncthreads();
  }
  if (i < NNODES) scanned[i] = s[t] - v;
  if (t == 255) partials[blockIdx.x] = s[255];
}

__global__ __launch_bounds__(512) void scan2(int* partials, int G){
  __shared__ int s[512];
  int t = threadIdx.x;
  int v = (t < G) ? partials[t] : 0;
  s[t] = v; __syncthreads();
  for (int off=1; off<512; off<<=1){
    int a = (t >= off) ? s[t-off] : 0;
    __syncthreads();
    s[t] += a;
    __syncthreads();
  }
  if (t < G) partials[t] = s[t] - v;
}

__global__ void scan3(const int* __restrict__ scanned, const int* __restrict__ partials,
                      int* __restrict__ row_ptr){
  int i = blockIdx.x*256 + threadIdx.x;
  if (i < NNODES){
    row_ptr[i] = scanned[i] + partials[i>>8];
  } else if (i == NNODES){
    row_ptr[NNODES] = NEDGES;
  }
}

// positional scatter: pos = row_ptr[dst] + rank[e]  (no atomics)
// meta64: lo32 = src, hi32 = weight fp32 bits (zero-cost decode in spmm3)
__global__ void scatter_kernel(const int* __restrict__ ei, const float* __restrict__ ew,
                               const int* __restrict__ flag,
                               const int* __restrict__ row_ptr, const int* __restrict__ rank,
                               u64* __restrict__ meta){
  int e = blockIdx.x*256 + threadIdx.x;
  if (e < NEDGES){
    int is64 = flag[0];
    int s = load_src(ei, is64, e);
    int d = load_dst(ei, is64, e);
    float w = __builtin_nontemporal_load(&ew[e]);
    if ((unsigned)d < NNODES && (unsigned)s < NNODES){
      int pos = row_ptr[d] + rank[e];
      if ((unsigned)pos < NEDGES){
        u64 pk = ((u64)__builtin_bit_cast(u32, w) << 32) | (u32)s;
        __builtin_nontemporal_store(pk, &meta[pos]);
      }
    }
  }
}

// ---------------- weight prep (fp32 -> bf16, transposed; cwt/w1t K pre-permuted by pi^-1) ----------------
__global__ void prep_w(const float* __restrict__ w0, const float* __restrict__ cw,
                       const float* __restrict__ w1,
                       short* __restrict__ w0t, short* __restrict__ cwt, short* __restrict__ w1t){
  int i = blockIdx.x*256 + threadIdx.x;
  const int n0 = NNETS*HF*HF;
  const int n1 = NNETS*NLAYERS*HF*HF;
  const int n2 = NNETS*OUTF*HF;
  if (i < n0){
    int net = i/(HF*HF), r = i%(HF*HF), c = r/HF, k = r%HF;
    w0t[i] = (short)f2bf(w0[(size_t)net*HF*HF + k*HF + c]);
  } else if (i < n0 + n1){
    int j = i - n0;
    int nl = j/(HF*HF), r = j%(HF*HF), c = r/HF, kp = r%HF;
    int k = ((kp&7)<<4) | (kp>>3);                 // pi^-1
    cwt[j] = (short)f2bf(cw[(size_t)nl*HF*HF + k*HF + c]);
  } else if (i < n0 + n1 + n2){
    int j = i - n0 - n1;
    int net = j/(OUTF*HF), r = j%(OUTF*HF), c = r/HF, kp = r%HF;
    int k = ((kp&7)<<4) | (kp>>3);                 // pi^-1
    w1t[j] = (short)f2bf(w1[(size_t)net*HF*OUTF + k*OUTF + c]);
  }
}

// ---------------- input GEMM: h0 = relu(x @ w0 + b0) -> h8/sc AND x08/scx (identical) ----------------
__global__ __launch_bounds__(256) void gemm_in(
    const float* __restrict__ x, const short* __restrict__ w0t, const float* __restrict__ b0,
    unsigned char* __restrict__ h8, float* __restrict__ sc,
    unsigned char* __restrict__ x08, float* __restrict__ scx)
{
  __shared__ short As[128*128];
  const int t = threadIdx.x;
  const int rowBase = blockIdx.x * 128;
  #pragma unroll
  for (int it=0; it<8; ++it){
    int r = it*16 + (t>>4);
    int k = (t&15)*8;
    int gr = rowBase + r;
    bf16x8 v = {0,0,0,0,0,0,0,0};
    if (gr < NNODES){
      f32x4 f0 = __builtin_nontemporal_load((const f32x4*)&x[(size_t)gr*128 + k]);
      f32x4 f1 = __builtin_nontemporal_load((const f32x4*)&x[(size_t)gr*128 + k + 4]);
      v[0]=(short)f2bf(f0[0]); v[1]=(short)f2bf(f0[1]); v[2]=(short)f2bf(f0[2]); v[3]=(short)f2bf(f0[3]);
      v[4]=(short)f2bf(f1[0]); v[5]=(short)f2bf(f1[1]); v[6]=(short)f2bf(f1[2]); v[7]=(short)f2bf(f1[3]);
    }
    *(bf16x8*)&As[r*128 + (k ^ ((r&7)<<3))] = v;
  }
  __syncthreads();

  const int wid = t>>6, lane = t&63;
  const int l16 = lane&15, kg = lane>>4;
  for (int net=0; net<NNETS; ++net){
    const short* Wt = w0t + (size_t)net*HF*HF;
    f32x4 acc[2][8];
    #pragma unroll
    for (int mt=0; mt<2; ++mt)
      #pragma unroll
      for (int nt=0; nt<8; ++nt){ acc[mt][nt][0]=0.f; acc[mt][nt][1]=0.f; acc[mt][nt][2]=0.f; acc[mt][nt][3]=0.f; }
    #pragma unroll
    for (int ks=0; ks<4; ++ks){
      int k0 = ks*32 + kg*8;
      bf16x8 a0, a1;
      { int r = wid*32 + l16;      a0 = *(const bf16x8*)&As[r*128 + (k0 ^ ((r&7)<<3))]; }
      { int r = wid*32 + 16 + l16; a1 = *(const bf16x8*)&As[r*128 + (k0 ^ ((r&7)<<3))]; }
      #pragma unroll
      for (int nt=0; nt<8; ++nt){
        bf16x8 b = *(const bf16x8*)&Wt[(size_t)(nt*16 + l16)*128 + k0];
        acc[0][nt] = __builtin_amdgcn_mfma_f32_16x16x32_bf16(a0, b, acc[0][nt], 0, 0, 0);
        acc[1][nt] = __builtin_amdgcn_mfma_f32_16x16x32_bf16(a1, b, acc[1][nt], 0, 0, 0);
      }
    }
    #pragma unroll
    for (int mt=0; mt<2; ++mt){
      #pragma unroll
      for (int j=0; j<4; ++j){
        int row = rowBase + wid*32 + mt*16 + kg*4 + j;
        float v[8]; float mx = 0.f;
        #pragma unroll
        for (int nt=0; nt<8; ++nt){
          float f = fmaxf(acc[mt][nt][j] + b0[net*HF + nt*16 + l16], 0.f);
          v[nt] = f; mx = fmaxf(mx, f);
        }
        #pragma unroll
        for (int off=1; off<16; off<<=1) mx = fmaxf(mx, __shfl_xor(mx, off));
        if (row < NNODES){
          float inv = (mx > 0.f) ? 255.f/mx : 0.f;
          u32 d0=0, d1=0;
          #pragma unroll
          for (int nt=0; nt<4; ++nt) d0 |= ((u32)(v[nt]*inv + 0.5f)) << (8*nt);
          #pragma unroll
          for (int nt=0; nt<4; ++nt) d1 |= ((u32)(v[4+nt]*inv + 0.5f)) << (8*nt);
          u32x2 pk; pk[0]=d0; pk[1]=d1;
          size_t off8 = (size_t)row*384 + net*128 + l16*8;
          *(u32x2*)&h8 [off8] = pk;
          *(u32x2*)&x08[off8] = pk;
          if (l16 == 0){ float s = mx * (1.f/255.f); sc[row*4 + net] = s; scx[row*4 + net] = s; }
        }
      }
    }
  }
}

// ---------------- mid GEMM: t = 0.9*agg8 + 0.1*x08 (dequant-combine in staging);
//                  h = relu((1-beta)*t + beta*(t @ cw)) -> h8/sc ----------------
__global__ __launch_bounds__(256) void gemm_mid(
    const unsigned char* __restrict__ agg8, const float* __restrict__ sca,
    const unsigned char* __restrict__ x08,  const float* __restrict__ scx,
    const short* __restrict__ W, const float beta,
    unsigned char* __restrict__ h8, float* __restrict__ sc)
{
  __shared__ short As[128*128];
  const int t = threadIdx.x;
  const int net = blockIdx.y;
  const int rowBase = blockIdx.x * 128;
  const short* Wt = W + (size_t)net*NLAYERS*HF*HF;

  #pragma unroll
  for (int it=0; it<8; ++it){
    int r = it*16 + (t>>4);
    int k = (t&15)*8;
    int gr = rowBase + r;
    bf16x8 v = {0,0,0,0,0,0,0,0};
    if (gr < NNODES){
      size_t off8 = (size_t)gr*384 + net*128 + k;
      u32x2 da = *(const u32x2*)&agg8[off8];
      u32x2 dx = *(const u32x2*)&x08[off8];
      float sa = 0.9f * sca[gr*4 + net];
      float sx = 0.1f * scx[gr*4 + net];
      #pragma unroll
      for (int j=0; j<4; ++j) v[j]   = (short)f2bf(sa*ub(da[0],j) + sx*ub(dx[0],j));
      #pragma unroll
      for (int j=0; j<4; ++j) v[4+j] = (short)f2bf(sa*ub(da[1],j) + sx*ub(dx[1],j));
    }
    *(bf16x8*)&As[r*128 + (k ^ ((r&7)<<3))] = v;
  }
  __syncthreads();

  const int wid = t>>6, lane = t&63;
  const int l16 = lane&15, kg = lane>>4;
  f32x4 acc[2][8];
  #pragma unroll
  for (int mt=0; mt<2; ++mt)
    #pragma unroll
    for (int nt=0; nt<8; ++nt){ acc[mt][nt][0]=0.f; acc[mt][nt][1]=0.f; acc[mt][nt][2]=0.f; acc[mt][nt][3]=0.f; }

  #pragma unroll
  for (int ks=0; ks<4; ++ks){
    int k0 = ks*32 + kg*8;
    bf16x8 a0, a1;
    { int r = wid*32 + l16;      a0 = *(const bf16x8*)&As[r*128 + (k0 ^ ((r&7)<<3))]; }
    { int r = wid*32 + 16 + l16; a1 = *(const bf16x8*)&As[r*128 + (k0 ^ ((r&7)<<3))]; }
    #pragma unroll
    for (int nt=0; nt<8; ++nt){
      bf16x8 b = *(const bf16x8*)&Wt[(size_t)(nt*16 + l16)*128 + k0];
      acc[0][nt] = __builtin_amdgcn_mfma_f32_16x16x32_bf16(a0, b, acc[0][nt], 0, 0, 0);
      acc[1][nt] = __builtin_amdgcn_mfma_f32_16x16x32_bf16(a1, b, acc[1][nt], 0, 0, 0);
    }
  }

  #pragma unroll
  for (int mt=0; mt<2; ++mt){
    #pragma unroll
    for (int j=0; j<4; ++j){
      int rl  = wid*32 + mt*16 + kg*4 + j;
      int row = rowBase + rl;
      float v[8]; float mx = 0.f;
      #pragma unroll
      for (int nt=0; nt<8; ++nt){
        int p = l16*8 + nt;                        // pi(col)
        float av = bf2f(As[rl*128 + (p ^ ((rl&7)<<3))]);
        float f = fmaxf((1.f-beta)*av + beta*acc[mt][nt][j], 0.f);
        v[nt] = f; mx = fmaxf(mx, f);
      }
      #pragma unroll
      for (int off=1; off<16; off<<=1) mx = fmaxf(mx, __shfl_xor(mx, off));
      if (row < NNODES){
        float inv = (mx > 0.f) ? 255.f/mx : 0.f;
        u32 d0=0, d1=0;
        #pragma unroll
        for (int nt=0; nt<4; ++nt) d0 |= ((u32)(v[nt]*inv + 0.5f)) << (8*nt);
        #pragma unroll
        for (int nt=0; nt<4; ++nt) d1 |= ((u32)(v[4+nt]*inv + 0.5f)) << (8*nt);
        u32x2 pk; pk[0]=d0; pk[1]=d1;
        *(u32x2*)&h8[(size_t)row*384 + net*128 + l16*8] = pk;
        if (l16 == 0) sc[row*4 + net] = mx * (1.f/255.f);
      }
    }
  }
}

// ---------------- output GEMM: dequant-stage h8, logits+log_softmax+ensemble mean ----------------
__global__ __launch_bounds__(256) void gemm_out(
    const unsigned char* __restrict__ h8, const float* __restrict__ sc,
    const short* __restrict__ w1t, const float* __restrict__ b1,
    float* __restrict__ out)
{
  __shared__ short As[128*128];
  const int t = threadIdx.x;
  const int rowBase = blockIdx.x * 128;
  const int wid = t>>6, lane = t&63;
  const int l16 = lane&15, kg = lane>>4;

  f32x4 sum[2][7];
  #pragma unroll
  for (int mt=0; mt<2; ++mt)
    #pragma unroll
    for (int nt=0; nt<7; ++nt){ sum[mt][nt][0]=0.f; sum[mt][nt][1]=0.f; sum[mt][nt][2]=0.f; sum[mt][nt][3]=0.f; }

  for (int net=0; net<NNETS; ++net){
    __syncthreads();
    #pragma unroll
    for (int it=0; it<8; ++it){
      int r = it*16 + (t>>4);
      int k = (t&15)*8;
      int gr = rowBase + r;
      bf16x8 v = {0,0,0,0,0,0,0,0};
      if (gr < NNODES){
        u32x2 d = *(const u32x2*)&h8[(size_t)gr*384 + net*128 + k];
        float s = sc[gr*4 + net];
        #pragma unroll
        for (int j=0; j<4; ++j) v[j]   = (short)f2bf(s * ub(d[0],j));
        #pragma unroll
        for (int j=0; j<4; ++j) v[4+j] = (short)f2bf(s * ub(d[1],j));
      }
      *(bf16x8*)&As[r*128 + (k ^ ((r&7)<<3))] = v;
    }
    __syncthreads();

    const short* Wt = w1t + (size_t)net*OUTF*HF;
    f32x4 acc[2][7];
    #pragma unroll
    for (int mt=0; mt<2; ++mt)
      #pragma unroll
      for (int nt=0; nt<7; ++nt){ acc[mt][nt][0]=0.f; acc[mt][nt][1]=0.f; acc[mt][nt][2]=0.f; acc[mt][nt][3]=0.f; }
    #pragma unroll
    for (int ks=0; ks<4; ++ks){
      int k0 = ks*32 + kg*8;
      bf16x8 a0, a1;
      { int r = wid*32 + l16;      a0 = *(const bf16x8*)&As[r*128 + (k0 ^ ((r&7)<<3))]; }
      { int r = wid*32 + 16 + l16; a1 = *(const bf16x8*)&As[r*128 + (k0 ^ ((r&7)<<3))]; }
      #pragma unroll
      for (int nt=0; nt<7; ++nt){
        bf16x8 b = *(const bf16x8*)&Wt[(size_t)(nt*16 + l16)*128 + k0];
        acc[0][nt] = __builtin_amdgcn_mfma_f32_16x16x32_bf16(a0, b, acc[0][nt], 0, 0, 0);
        acc[1][nt] = __builtin_amdgcn_mfma_f32_16x16x32_bf16(a1, b, acc[1][nt], 0, 0, 0);
      }
    }
    #pragma unroll
    for (int mt=0; mt<2; ++mt)
      #pragma unroll
      for (int nt=0; nt<7; ++nt){
        float b = b1[net*OUTF + nt*16 + l16];
        #pragma unroll
        for (int j=0; j<4; ++j) acc[mt][nt][j] += b;
      }
    #pragma unroll
    for (int mt=0; mt<2; ++mt){
      #pragma unroll
      for (int j=0; j<4; ++j){
        float m = -3.4e38f;
        #pragma unroll
        for (int nt=0; nt<7; ++nt) m = fmaxf(m, acc[mt][nt][j]);
        #pragma unroll
        for (int k=1; k<16; k<<=1) m = fmaxf(m, __shfl_xor(m, k));
        float e = 0.f;
        #pragma unroll
        for (int nt=0; nt<7; ++nt) e += expf(acc[mt][nt][j] - m);
        #pragma unroll
        for (int k=1; k<16; k<<=1) e += __shfl_xor(e, k);
        float lse = m + logf(e);
        #pragma unroll
        for (int nt=0; nt<7; ++nt) sum[mt][nt][j] += acc[mt][nt][j] - lse;
      }
    }
  }

  #pragma unroll
  for (int mt=0; mt<2; ++mt){
    #pragma unroll
    for (int nt=0; nt<7; ++nt){
      #pragma unroll
      for (int j=0; j<4; ++j){
        int row = rowBase + wid*32 + mt*16 + kg*4 + j;
        if (row < NNODES)
          __builtin_nontemporal_store(sum[mt][nt][j] * (1.f/3.f),
                                      &out[(size_t)row*OUTF + nt*16 + l16]);
      }
    }
  }
}

// ---------------- SpMM (pure gather, asm VALU core, zero-decode meta64): agg8 = quant(A @ h8) ----------------
__global__ __launch_bounds__(256) void spmm3(
    const int* __restrict__ row_ptr, const u64* __restrict__ meta,
    const unsigned char* __restrict__ h8, const float* __restrict__ sc,
    unsigned char* __restrict__ agg8, float* __restrict__ sca)
{
  int node = blockIdx.x*4 + (threadIdx.x>>6);
  int lane = threadIdx.x & 63;
  int q    = lane >> 4;
  int l16  = lane & 15;
  const u32 base_l = (u32)l16*8;
  int start = row_ptr[node], end = row_ptr[node+1];
  f32x2 acc[3][4];
  #pragma unroll
  for (int n=0;n<3;++n)
    #pragma unroll
    for (int p=0;p<4;++p){ acc[n][p][0]=0.f; acc[n][p][1]=0.f; }

  int e = start + q;
  for (; e + 4 < end; e += 8){
    u64 m0 = __builtin_nontemporal_load(&meta[e]);
    u64 m1 = __builtin_nontemporal_load(&meta[e+4]);
    u32 s0 = (u32)m0, s1 = (u32)m1;
    u32 o0 = (s0<<8) + (s0<<7) + base_l;     // s0*384 + l16*8
    u32 o1 = (s1<<8) + (s1<<7) + base_l;
    float w0 = __builtin_bit_cast(float, (u32)(m0 >> 32));
    float w1 = __builtin_bit_cast(float, (u32)(m1 >> 32));
    f32x4 c0 = *(const f32x4*)&sc[s0*4];
    f32x4 c1 = *(const f32x4*)&sc[s1*4];
    u32x2 a0 = *(const u32x2*)(h8 + o0);
    u32x2 a1 = *(const u32x2*)(h8 + o0 + 128);
    u32x2 a2 = *(const u32x2*)(h8 + o0 + 256);
    u32x2 b0 = *(const u32x2*)(h8 + o1);
    u32x2 b1 = *(const u32x2*)(h8 + o1 + 128);
    u32x2 b2 = *(const u32x2*)(h8 + o1 + 256);
    f32x2 W00 = {w0*c0[0], w0*c0[0]}, W01 = {w0*c0[1], w0*c0[1]}, W02 = {w0*c0[2], w0*c0[2]};
    f32x2 W10 = {w1*c1[0], w1*c1[0]}, W11 = {w1*c1[1], w1*c1[1]}, W12 = {w1*c1[2], w1*c1[2]};
    mac4(acc[0][0], acc[0][1], W00, a0[0]);
    mac4(acc[0][2], acc[0][3], W00, a0[1]);
    mac4(acc[1][0], acc[1][1], W01, a1[0]);
    mac4(acc[1][2], acc[1][3], W01, a1[1]);
    mac4(acc[2][0], acc[2][1], W02, a2[0]);
    mac4(acc[2][2], acc[2][3], W02, a2[1]);
    mac4(acc[0][0], acc[0][1], W10, b0[0]);
    mac4(acc[0][2], acc[0][3], W10, b0[1]);
    mac4(acc[1][0], acc[1][1], W11, b1[0]);
    mac4(acc[1][2], acc[1][3], W11, b1[1]);
    mac4(acc[2][0], acc[2][1], W12, b2[0]);
    mac4(acc[2][2], acc[2][3], W12, b2[1]);
  }
  for (; e < end; e += 4){
    u64 m0 = __builtin_nontemporal_load(&meta[e]);
    u32 s0 = (u32)m0;
    u32 o0 = (s0<<8) + (s0<<7) + base_l;
    float w0 = __builtin_bit_cast(float, (u32)(m0 >> 32));
    f32x4 c0 = *(const f32x4*)&sc[s0*4];
    u32x2 a0 = *(const u32x2*)(h8 + o0);
    u32x2 a1 = *(const u32x2*)(h8 + o0 + 128);
    u32x2 a2 = *(const u32x2*)(h8 + o0 + 256);
    f32x2 W00 = {w0*c0[0], w0*c0[0]}, W01 = {w0*c0[1], w0*c0[1]}, W02 = {w0*c0[2], w0*c0[2]};
    mac4(acc[0][0], acc[0][1], W00, a0[0]);
    mac4(acc[0][2], acc[0][3], W00, a0[1]);
    mac4(acc[1][0], acc[1][1], W01, a1[0]);
    mac4(acc[1][2], acc[1][3], W01, a1[1]);
    mac4(acc[2][0], acc[2][1], W02, a2[0]);
    mac4(acc[2][2], acc[2][3], W02, a2[1]);
  }
  #pragma unroll
  for (int n=0;n<3;++n)
    #pragma unroll
    for (int p=0;p<4;++p){
      acc[n][p][0] += __shfl_xor(acc[n][p][0], 16);
      acc[n][p][1] += __shfl_xor(acc[n][p][1], 16);
      acc[n][p][0] += __shfl_xor(acc[n][p][0], 32);
      acc[n][p][1] += __shfl_xor(acc[n][p][1], 32);
    }
  if (q < 3){
    float v[8];
    #pragma unroll
    for (int p=0;p<4;++p){ v[2*p] = acc[q][p][0]; v[2*p+1] = acc[q][p][1]; }
    float mx = 0.f;
    #pragma unroll
    for (int j=0;j<8;++j) mx = fmaxf(mx, v[j]);
    #pragma unroll
    for (int off=1; off<16; off<<=1) mx = fmaxf(mx, __shfl_xor(mx, off));
    float inv = (mx > 0.f) ? 255.f/mx : 0.f;
    u32 d0=0, d1=0;
    #pragma unroll
    for (int j=0;j<4;++j) d0 |= ((u32)(v[j]*inv + 0.5f)) << (8*j);
    #pragma unroll
    for (int j=0;j<4;++j) d1 |= ((u32)(v[4+j]*inv + 0.5f)) << (8*j);
    u32x2 pk; pk[0]=d0; pk[1]=d1;
    *(u32x2*)&agg8[(size_t)node*384 + q*128 + base_l] = pk;
    if (l16 == 0) sca[node*4 + q] = mx * (1.f/255.f);
  }
}

extern "C" void kernel_launch(void* const* d_in, const int* in_sizes, int n_in,
                              void* d_out, int out_size, void* d_ws, size_t ws_size,
                              hipStream_t stream){
  const float* x  = (const float*)d_in[0];
  const int*   ei = (const int*)d_in[1];
  const float* ew = (const float*)d_in[2];
  const float* w0 = (const float*)d_in[3];
  const float* b0 = (const float*)d_in[4];
  const float* w1 = (const float*)d_in[5];
  const float* b1 = (const float*)d_in[6];
  const float* cw = (const float*)d_in[7];
  float* out = (float*)d_out;

  char* ws = (char*)d_ws;
  size_t o = 0;
  auto alloc = [&](size_t b){ size_t r = o; o += (b + 255) & ~(size_t)255; return r; };
  int*   flag     = (int*)(ws + alloc(256));
  int*   counts   = (int*)(ws + alloc((size_t)NNODES*4));
  int*   scanned  = (int*)(ws + alloc((size_t)NNODES*4));
  int*   row_ptr  = (int*)(ws + alloc((size_t)(NNODES+1)*4));
  int*   partials = (int*)(ws + alloc(512*4));
  int*   rank     = (int*)(ws + alloc((size_t)NEDGES*4));
  u64*   meta     = (u64*)(ws + alloc((size_t)NEDGES*8));
  short* w0t = (short*)(ws + alloc((size_t)NNETS*HF*HF*2));
  short* cwt = (short*)(ws + alloc((size_t)NNETS*NLAYERS*HF*HF*2));
  short* w1t = (short*)(ws + alloc((size_t)NNETS*OUTF*HF*2));
  unsigned char* h8   = (unsigned char*)(ws + alloc((size_t)NNODES*NNETS*128));
  float* sc  = (float*)(ws + alloc((size_t)NNODES*4*4));
  unsigned char* x08  = (unsigned char*)(ws + alloc((size_t)NNODES*NNETS*128));
  float* scx = (float*)(ws + alloc((size_t)NNODES*4*4));
  unsigned char* agg8 = (unsigned char*)(ws + alloc((size_t)NNODES*NNETS*128));
  float* sca = (float*)(ws + alloc((size_t)NNODES*4*4));
  (void)ws_size; (void)in_sizes; (void)n_in; (void)out_size;
  // total ws use ~143 MB

  hipMemsetAsync(counts, 0, (size_t)NNODES*4, stream);
  detect_fmt    <<<1,   64,  0, stream>>>((const u64*)ei, flag);
  hist_kernel   <<<6250,256, 0, stream>>>(ei, flag, counts, rank);
  scan1         <<<391, 256, 0, stream>>>(counts, scanned, partials);
  scan2         <<<1,   512, 0, stream>>>(partials, 391);
  scan3         <<<391, 256, 0, stream>>>(scanned, partials, row_ptr);
  scatter_kernel<<<6250,256, 0, stream>>>(ei, ew, flag, row_ptr, rank, meta);

  prep_w<<<1128, 256, 0, stream>>>(w0, cw, w1, w0t, cwt, w1t);

  gemm_in<<<782, 256, 0, stream>>>(x, w0t, b0, h8, sc, x08, scx);
  for (int l=0; l<NLAYERS; ++l){
    float beta = logf(0.5f/(float)(l+1) + 1.0f);
    spmm3<<<25000, 256, 0, stream>>>(row_ptr, meta, h8, sc, agg8, sca);
    gemm_mid<<<dim3(782,3), 256, 0, stream>>>(agg8, sca, x08, scx,
                                              cwt + (size_t)l*HF*HF, beta, h8, sc);
  }
  gemm_out<<<782, 256, 0, stream>>>(h8, sc, w1t, b1, out);
}